// Round 2
// baseline (13683.685 us; speedup 1.0000x reference)
//
#include <hip/hip_runtime.h>

typedef unsigned short u16;
typedef unsigned int   u32;

#define DIMC   192
#define HH     56
#define WSZ    7
#define SSH    3
#define NHEAD  6
#define HDIM   32
#define NTOK   49
#define NWIN_T 2048            // 32 batches * 8 * 8 windows
#define HIDDEN 768
#define LTOT   3136            // 56*56

__device__ __forceinline__ float bf2f(u16 u) {
    union { u32 i; float f; } v; v.i = ((u32)u) << 16; return v.f;
}
__device__ __forceinline__ u16 f2bf(float f) {
    union { float ff; u32 i; } v; v.ff = f;
    u32 x = v.i;
    return (u16)((x + 0x7FFFu + ((x >> 16) & 1u)) >> 16);  // RNE
}

template<bool F32> __device__ __forceinline__ float ldin(const void* p, size_t i) {
    if constexpr (F32) return reinterpret_cast<const float*>(p)[i];
    else               return bf2f(reinterpret_cast<const u16*>(p)[i]);
}
template<bool F32> __device__ __forceinline__ void stout(void* p, size_t i, float v) {
    if constexpr (F32) reinterpret_cast<float*>(p)[i] = v;
    else               reinterpret_cast<u16*>(p)[i] = f2bf(v);
}

// ---------------------------------------------------------------------------
// Fully fused Swin block: one workgroup (256 thr) per 7x7 window.
// LDS regions:
//   A: 49*192 bf16 (18816 B)  xn -> O -> xln
//   B: 49*576 bf16 (56448 B)  qkv -> (xw | h-chunk)
//   C: 49*52  f32  (10192 B)  attention scores
// ---------------------------------------------------------------------------
template<bool F32>
__device__ void swin_body(const void* __restrict__ x,
                          const void* __restrict__ qkv_w, const void* __restrict__ qkv_b,
                          const void* __restrict__ proj_w, const void* __restrict__ proj_b,
                          const void* __restrict__ g1, const void* __restrict__ be1,
                          const void* __restrict__ g2, const void* __restrict__ be2,
                          const void* __restrict__ w1, const void* __restrict__ b1,
                          const void* __restrict__ w2, const void* __restrict__ b2,
                          void* __restrict__ out,
                          u16* s_A, u16* s_B, float* s_S)
{
    const int wid = blockIdx.x;
    const int b  = wid >> 6;
    const int wi = (wid >> 3) & 7;
    const int wj = wid & 7;
    const int tid  = threadIdx.x;
    const int wave = tid >> 6;
    const int lane = tid & 63;

    // ---- Phase 1: gather (cyclic shift -SS) + LayerNorm1 -> A (bf16) ----
    for (int t = wave; t < NTOK; t += 4) {
        const int pi = t / 7, pj = t - pi * 7;
        const int si = (wi * WSZ + pi + SSH) % HH;
        const int sj = (wj * WSZ + pj + SSH) % HH;
        const size_t base = ((size_t)b * LTOT + si * HH + sj) * DIMC;
        float v0 = ldin<F32>(x, base + lane);
        float v1 = ldin<F32>(x, base + lane + 64);
        float v2 = ldin<F32>(x, base + lane + 128);
        float s  = v0 + v1 + v2;
        float s2 = v0 * v0 + v1 * v1 + v2 * v2;
#pragma unroll
        for (int off = 32; off > 0; off >>= 1) {
            s  += __shfl_xor(s,  off);
            s2 += __shfl_xor(s2, off);
        }
        const float mu   = s * (1.f / 192.f);
        const float rstd = rsqrtf(s2 * (1.f / 192.f) - mu * mu + 1e-5f);
        s_A[t*DIMC + lane      ] = f2bf((v0-mu)*rstd*ldin<F32>(g1,lane)     + ldin<F32>(be1,lane));
        s_A[t*DIMC + lane + 64 ] = f2bf((v1-mu)*rstd*ldin<F32>(g1,lane+64)  + ldin<F32>(be1,lane+64));
        s_A[t*DIMC + lane + 128] = f2bf((v2-mu)*rstd*ldin<F32>(g1,lane+128) + ldin<F32>(be1,lane+128));
    }
    __syncthreads();

    // ---- Phase 2: QKV = xn @ qkv_w + qkv_b -> B (bf16) ----
    {
        const u32* xn2 = reinterpret_cast<const u32*>(s_A);
        for (int n = tid; n < 3 * DIMC; n += 256) {
            const float bias = ldin<F32>(qkv_b, n);
            for (int t0 = 0; t0 < NTOK; t0 += 16) {
                const int tn = (NTOK - t0) < 16 ? (NTOK - t0) : 16;
                float acc[16];
#pragma unroll
                for (int i = 0; i < 16; i++) acc[i] = 0.f;
                for (int k = 0; k < DIMC; k += 2) {
                    const float wv0 = ldin<F32>(qkv_w, (size_t)k * (3*DIMC) + n);
                    const float wv1 = ldin<F32>(qkv_w, (size_t)(k+1) * (3*DIMC) + n);
#pragma unroll
                    for (int i = 0; i < 16; i++) {
                        if (i < tn) {
                            u32 u = xn2[((t0 + i) * DIMC + k) >> 1];
                            acc[i] += bf2f((u16)u) * wv0 + bf2f((u16)(u >> 16)) * wv1;
                        }
                    }
                }
                for (int i = 0; i < tn; i++)
                    s_B[(t0 + i) * (3*DIMC) + n] = f2bf(acc[i] + bias);
            }
        }
    }
    __syncthreads();

    // ---- Phase 3: per-head attention; O overwrites A ----
    const float scale = 0.1767766952966369f;  // 1/sqrt(32)
    for (int h = 0; h < NHEAD; h++) {
        for (int idx = tid; idx < NTOK * NTOK; idx += 256) {
            const int i = idx / NTOK, j = idx - i * NTOK;
            const u32* qp = reinterpret_cast<const u32*>(&s_B[i*(3*DIMC) + h*HDIM]);
            const u32* kp = reinterpret_cast<const u32*>(&s_B[j*(3*DIMC) + DIMC + h*HDIM]);
            float acc = 0.f;
#pragma unroll
            for (int d = 0; d < HDIM / 2; d++) {
                const u32 qu = qp[d], ku = kp[d];
                acc += bf2f((u16)qu) * bf2f((u16)ku)
                     + bf2f((u16)(qu >> 16)) * bf2f((u16)(ku >> 16));
            }
            s_S[i * 52 + j] = acc * scale;
        }
        __syncthreads();
        if (tid < NTOK) {
            float m = -1e30f;
            for (int j = 0; j < NTOK; j++) m = fmaxf(m, s_S[tid*52 + j]);
            float sum = 0.f;
            for (int j = 0; j < NTOK; j++) {
                float e = __expf(s_S[tid*52 + j] - m);
                s_S[tid*52 + j] = e;
                sum += e;
            }
            const float inv = 1.f / sum;
            for (int j = 0; j < NTOK; j++) s_S[tid*52 + j] *= inv;
        }
        __syncthreads();
        for (int idx = tid; idx < NTOK * HDIM; idx += 256) {
            const int i = idx >> 5, d = idx & 31;
            float acc = 0.f;
            for (int j = 0; j < NTOK; j++)
                acc += s_S[i*52 + j] * bf2f(s_B[j*(3*DIMC) + 2*DIMC + h*HDIM + d]);
            s_A[i * DIMC + h * HDIM + d] = f2bf(acc);
        }
        __syncthreads();
    }

    // ---- Phase 4: xw = O @ proj_w + proj_b -> B[0 : 49*192) (bf16) ----
    if (tid < DIMC) {
        const int n = tid;
        const float bias = ldin<F32>(proj_b, n);
        const u32* O2 = reinterpret_cast<const u32*>(s_A);
        for (int t0 = 0; t0 < NTOK; t0 += 16) {
            const int tn = (NTOK - t0) < 16 ? (NTOK - t0) : 16;
            float acc[16];
#pragma unroll
            for (int i = 0; i < 16; i++) acc[i] = 0.f;
            for (int k = 0; k < DIMC; k += 2) {
                const float wv0 = ldin<F32>(proj_w, (size_t)k * DIMC + n);
                const float wv1 = ldin<F32>(proj_w, (size_t)(k+1) * DIMC + n);
#pragma unroll
                for (int i = 0; i < 16; i++) {
                    if (i < tn) {
                        u32 u = O2[((t0 + i) * DIMC + k) >> 1];
                        acc[i] += bf2f((u16)u) * wv0 + bf2f((u16)(u >> 16)) * wv1;
                    }
                }
            }
            for (int i = 0; i < tn; i++)
                s_B[(t0 + i) * DIMC + n] = f2bf(acc[i] + bias);
        }
    }
    __syncthreads();

    // ---- Phase 5: LN2(xw) -> A (bf16); xw stays in B as the residual ----
    for (int t = wave; t < NTOK; t += 4) {
        float v0 = bf2f(s_B[t*DIMC + lane      ]);
        float v1 = bf2f(s_B[t*DIMC + lane + 64 ]);
        float v2 = bf2f(s_B[t*DIMC + lane + 128]);
        float s  = v0 + v1 + v2;
        float s2 = v0 * v0 + v1 * v1 + v2 * v2;
#pragma unroll
        for (int off = 32; off > 0; off >>= 1) {
            s  += __shfl_xor(s,  off);
            s2 += __shfl_xor(s2, off);
        }
        const float mu   = s * (1.f / 192.f);
        const float rstd = rsqrtf(s2 * (1.f / 192.f) - mu * mu + 1e-5f);
        s_A[t*DIMC + lane      ] = f2bf((v0-mu)*rstd*ldin<F32>(g2,lane)     + ldin<F32>(be2,lane));
        s_A[t*DIMC + lane + 64 ] = f2bf((v1-mu)*rstd*ldin<F32>(g2,lane+64)  + ldin<F32>(be2,lane+64));
        s_A[t*DIMC + lane + 128] = f2bf((v2-mu)*rstd*ldin<F32>(g2,lane+128) + ldin<F32>(be2,lane+128));
    }
    __syncthreads();

    // ---- Phase 6: MLP in 4 token-groups of <=13; h-chunk in B[49*192 ...) ----
    u16* s_h = s_B + NTOK * DIMC;   // 13*768*2 = 19968 B chunk, fits in B
    for (int tg = 0; tg < 4; tg++) {
        const int tbase = tg * 13;
        const int tcnt  = (NTOK - tbase) < 13 ? (NTOK - tbase) : 13;
        // GEMM1 + exact gelu
        {
            const u32* xl2 = reinterpret_cast<const u32*>(s_A);
            for (int n = tid; n < HIDDEN; n += 256) {
                float acc[13];
#pragma unroll
                for (int i = 0; i < 13; i++) acc[i] = 0.f;
                for (int k = 0; k < DIMC; k += 2) {
                    const float wv0 = ldin<F32>(w1, (size_t)k * HIDDEN + n);
                    const float wv1 = ldin<F32>(w1, (size_t)(k+1) * HIDDEN + n);
#pragma unroll
                    for (int i = 0; i < 13; i++) {
                        if (i < tcnt) {
                            u32 u = xl2[((tbase + i) * DIMC + k) >> 1];
                            acc[i] += bf2f((u16)u) * wv0 + bf2f((u16)(u >> 16)) * wv1;
                        }
                    }
                }
                const float bb = ldin<F32>(b1, n);
                for (int i = 0; i < tcnt; i++) {
                    const float z = acc[i] + bb;
                    const float gel = 0.5f * z * (1.f + erff(z * 0.70710678118f));
                    s_h[i * HIDDEN + n] = f2bf(gel);
                }
            }
        }
        __syncthreads();
        // GEMM2 + bias + residual(xw) + scatter (reverse shift +SS)
        if (tid < DIMC) {
            const int n = tid;
            const u32* h2 = reinterpret_cast<const u32*>(s_h);
            float acc[13];
#pragma unroll
            for (int i = 0; i < 13; i++) acc[i] = 0.f;
            for (int k = 0; k < HIDDEN; k += 2) {
                const float wv0 = ldin<F32>(w2, (size_t)k * DIMC + n);
                const float wv1 = ldin<F32>(w2, (size_t)(k+1) * DIMC + n);
#pragma unroll
                for (int i = 0; i < 13; i++) {
                    if (i < tcnt) {
                        u32 u = h2[(i * HIDDEN + k) >> 1];
                        acc[i] += bf2f((u16)u) * wv0 + bf2f((u16)(u >> 16)) * wv1;
                    }
                }
            }
            const float bb = ldin<F32>(b2, n);
            for (int i = 0; i < tcnt; i++) {
                const int t = tbase + i;
                const int pi = t / 7, pj = t - pi * 7;
                const int di = (wi * WSZ + pi + SSH) % HH;
                const int dj = (wj * WSZ + pj + SSH) % HH;
                const float res = bf2f(s_B[t * DIMC + n]);
                stout<F32>(out, ((size_t)b * LTOT + di * HH + dj) * DIMC + n,
                           acc[i] + bb + res);
            }
        }
        __syncthreads();
    }
}

__global__ __launch_bounds__(256, 1)
void swin_kernel(const void* __restrict__ x,
                 const void* __restrict__ qkv_w, const void* __restrict__ qkv_b,
                 const void* __restrict__ proj_w, const void* __restrict__ proj_b,
                 const void* __restrict__ g1, const void* __restrict__ be1,
                 const void* __restrict__ g2, const void* __restrict__ be2,
                 const void* __restrict__ w1, const void* __restrict__ b1,
                 const void* __restrict__ w2, const void* __restrict__ b2,
                 void* __restrict__ out)
{
    __shared__ __align__(16) u16  s_A[NTOK * DIMC];
    __shared__ __align__(16) u16  s_B[NTOK * 3 * DIMC];
    __shared__ __align__(16) float s_S[NTOK * 52];

    // dtype probe: g1 == ones. fp32 word0 = 0x3F800000, bf16 word0 = 0x3F803F80.
    const u32 gw = reinterpret_cast<const u32*>(g1)[0];
    if (gw == 0x3F800000u)
        swin_body<true >(x, qkv_w, qkv_b, proj_w, proj_b, g1, be1, g2, be2,
                         w1, b1, w2, b2, out, s_A, s_B, s_S);
    else
        swin_body<false>(x, qkv_w, qkv_b, proj_w, proj_b, g1, be1, g2, be2,
                         w1, b1, w2, b2, out, s_A, s_B, s_S);
}

extern "C" void kernel_launch(void* const* d_in, const int* in_sizes, int n_in,
                              void* d_out, int out_size, void* d_ws, size_t ws_size,
                              hipStream_t stream)
{
    swin_kernel<<<NWIN_T, 256, 0, stream>>>(
        d_in[0], d_in[1], d_in[2], d_in[3], d_in[4], d_in[5], d_in[6],
        d_in[7], d_in[8], d_in[9], d_in[10], d_in[11], d_in[12], d_out);
}

// Round 5
// 1106.244 us; speedup vs baseline: 12.3695x; 12.3695x over previous
//
#include <hip/hip_runtime.h>

typedef unsigned short u16;
typedef unsigned int   u32;
typedef __attribute__((ext_vector_type(8))) short bf16x8;
typedef __attribute__((ext_vector_type(4))) float f32x4;

#define DIMC   192
#define HH     56
#define WSZ    7
#define SSH    3
#define NHEAD  6
#define NTOK   49
#define NWIN_T 2048
#define HIDDEN 768
#define LTOT   3136

// LDS row strides (elements)
#define LDA    200
#define LDQ    584
#define LDSS   60

// ws layout (u16 elems): per weight col, [K hi | K lo] contiguous (stride 2K)
#define OFF_QKV 0                         // 576 cols * 384
#define OFF_PW  221184                    // + 192 * 384
#define OFF_W1  294912                    // + 768 * 384
#define OFF_W2  589824                    // + 192 * 1536
#define WS_ELEMS 884736
#define WS_BYTES (WS_ELEMS * 2)

#define MFMA(a,b,c) __builtin_amdgcn_mfma_f32_16x16x32_bf16((a),(b),(c),0,0,0)

__device__ __forceinline__ float bf2f(u16 u) {
    union { u32 i; float f; } v; v.i = ((u32)u) << 16; return v.f;
}
__device__ __forceinline__ u16 f2bf(float f) {
    union { float ff; u32 i; } v; v.ff = f;
    u32 x = v.i;
    return (u16)((x + 0x7FFFu + ((x >> 16) & 1u)) >> 16);  // RNE
}
__device__ __forceinline__ void split_store(u16* hi, u16* lo, float w) {
    u16 h = f2bf(w);
    *hi = h;
    *lo = f2bf(w - bf2f(h));
}

// ---------------------------------------------------------------------------
// Prep: fp32 [K][N] -> split bf16 W^T stored [N][ hi[0:K] | lo[0:K] ].
// ---------------------------------------------------------------------------
__global__ void cvt_weights(const float* __restrict__ qkv_w,
                            const float* __restrict__ proj_w,
                            const float* __restrict__ w1,
                            const float* __restrict__ w2,
                            u16* __restrict__ ws)
{
    const int idx = blockIdx.x * blockDim.x + threadIdx.x;
    const int stride = gridDim.x * blockDim.x;
    for (int i = idx; i < 110592; i += stride) {        // qkv [192][576]
        int k = i / 576, n = i - k * 576;
        u16* base = ws + OFF_QKV + (size_t)n * 384;
        split_store(base + k, base + 192 + k, qkv_w[i]);
    }
    for (int i = idx; i < 36864; i += stride) {         // proj [192][192]
        int k = i / 192, n = i - k * 192;
        u16* base = ws + OFF_PW + (size_t)n * 384;
        split_store(base + k, base + 192 + k, proj_w[i]);
    }
    for (int i = idx; i < 147456; i += stride) {        // w1 [192][768]
        int k = i / 768, n = i - k * 768;
        u16* base = ws + OFF_W1 + (size_t)n * 384;
        split_store(base + k, base + 192 + k, w1[i]);
    }
    for (int i = idx; i < 147456; i += stride) {        // w2 [768][192]
        int k = i / 192, n = i - k * 192;
        u16* base = ws + OFF_W2 + (size_t)n * 1536;
        split_store(base + k, base + 768 + k, w2[i]);
    }
}

// ---------------------------------------------------------------------------
// Fused Swin block: MFMA (split-precision weights) for QKV/proj/MLP,
// round-2 scalar attention (fp32 S,P) for QK^T/softmax/PV.
// ---------------------------------------------------------------------------
__global__ __launch_bounds__(256, 1)
void swin_mfma(const float* __restrict__ x,
               const float* __restrict__ qkv_b, const float* __restrict__ proj_b,
               const float* __restrict__ g1, const float* __restrict__ be1,
               const float* __restrict__ g2, const float* __restrict__ be2,
               const float* __restrict__ b1, const float* __restrict__ b2,
               const u16* __restrict__ wsw, float* __restrict__ out)
{
    __shared__ __align__(16) u16   s_A[64 * LDA];   // xn -> O -> xln  (25.6 KB)
    __shared__ __align__(16) u16   s_B[64 * LDQ];   // qkv -> (xw | h) (74.8 KB)
    __shared__ __align__(16) float s_S[64 * LDSS];  // scores/probs    (15.4 KB)

    u16* const s_XW = s_B;                  // [64][LDA] after attention
    u16* const s_H  = s_B + 64 * LDA;       // [64][LDA] MLP hidden chunk

    const int wid = blockIdx.x;
    const int b  = wid >> 6;
    const int wi = (wid >> 3) & 7;
    const int wj = wid & 7;
    const int tid  = threadIdx.x;
    const int wv   = tid >> 6;
    const int lane = tid & 63;
    const int ar   = lane & 15;
    const int ak   = (lane >> 4) << 3;
    const int rg0  = (lane >> 4) << 2;

    const u16* Wqkvt = wsw + OFF_QKV;
    const u16* Wpt   = wsw + OFF_PW;
    const u16* W1t   = wsw + OFF_W1;
    const u16* W2t   = wsw + OFF_W2;

    // ---- P1: gather (shift -SSH) + LN1 -> s_A; pad rows 49..63 zeroed ----
    for (int t = wv; t < 64; t += 4) {
        if (t < NTOK) {
            const int pi = t / 7, pj = t - pi * 7;
            const int si = (wi * WSZ + pi + SSH) % HH;
            const int sj = (wj * WSZ + pj + SSH) % HH;
            const float* src = x + ((size_t)b * LTOT + si * HH + sj) * DIMC;
            float v0 = src[lane], v1 = src[lane + 64], v2 = src[lane + 128];
            float s  = v0 + v1 + v2;
            float s2 = v0 * v0 + v1 * v1 + v2 * v2;
#pragma unroll
            for (int off = 32; off > 0; off >>= 1) {
                s  += __shfl_xor(s,  off);
                s2 += __shfl_xor(s2, off);
            }
            const float mu   = s * (1.f / 192.f);
            const float rstd = rsqrtf(s2 * (1.f / 192.f) - mu * mu + 1e-5f);
            s_A[t*LDA + lane      ] = f2bf((v0-mu)*rstd*g1[lane]     + be1[lane]);
            s_A[t*LDA + lane + 64 ] = f2bf((v1-mu)*rstd*g1[lane+64]  + be1[lane+64]);
            s_A[t*LDA + lane + 128] = f2bf((v2-mu)*rstd*g1[lane+128] + be1[lane+128]);
        } else {
            s_A[t*LDA + lane] = 0; s_A[t*LDA + lane + 64] = 0; s_A[t*LDA + lane + 128] = 0;
        }
    }
    __syncthreads();

    // ---- P2: QKV = xn @ (Whi+Wlo) + b  (MFMA) -> s_B [64][LDQ] ----
    {
        bf16x8 a[4][6];
#pragma unroll
        for (int mt = 0; mt < 4; mt++)
#pragma unroll
            for (int kk = 0; kk < 6; kk++)
                a[mt][kk] = *(const bf16x8*)&s_A[(mt*16 + ar)*LDA + kk*32 + ak];
        for (int nt = wv; nt < 36; nt += 4) {
            const int col = nt * 16 + ar;
            const float bias = qkv_b[col];
            const u16* wc = Wqkvt + (size_t)col * 384;
            bf16x8 bh[6], bl[6];
#pragma unroll
            for (int kk = 0; kk < 6; kk++) {
                bh[kk] = *(const bf16x8*)&wc[kk*32 + ak];
                bl[kk] = *(const bf16x8*)&wc[192 + kk*32 + ak];
            }
            f32x4 acc[4];
#pragma unroll
            for (int mt = 0; mt < 4; mt++) acc[mt] = 0;
#pragma unroll
            for (int kk = 0; kk < 6; kk++)
#pragma unroll
                for (int mt = 0; mt < 4; mt++) {
                    acc[mt] = MFMA(a[mt][kk], bh[kk], acc[mt]);
                    acc[mt] = MFMA(a[mt][kk], bl[kk], acc[mt]);
                }
#pragma unroll
            for (int mt = 0; mt < 4; mt++)
#pragma unroll
                for (int rg = 0; rg < 4; rg++)
                    s_B[(mt*16 + rg0 + rg)*LDQ + col] = f2bf(acc[mt][rg] + bias);
        }
    }
    __syncthreads();

    // ---- P3: attention per head — round-2 scalar path (fp32 S,P) ----
    // O rows <49 -> s_A; s_A pad rows keep their zeros from P1.
    const float scale = 0.1767766952966369f;   // 1/sqrt(32)
    for (int h = 0; h < NHEAD; h++) {
        for (int idx = tid; idx < NTOK * NTOK; idx += 256) {
            const int i = idx / NTOK, j = idx - i * NTOK;
            const u32* qp = reinterpret_cast<const u32*>(&s_B[i*LDQ + h*32]);
            const u32* kp = reinterpret_cast<const u32*>(&s_B[j*LDQ + DIMC + h*32]);
            float acc = 0.f;
#pragma unroll
            for (int d = 0; d < 16; d++) {
                const u32 qu = qp[d], ku = kp[d];
                acc += bf2f((u16)qu) * bf2f((u16)ku)
                     + bf2f((u16)(qu >> 16)) * bf2f((u16)(ku >> 16));
            }
            s_S[i*LDSS + j] = acc * scale;
        }
        __syncthreads();
        if (tid < NTOK) {
            float m = -1e30f;
            for (int j = 0; j < NTOK; j++) m = fmaxf(m, s_S[tid*LDSS + j]);
            float sum = 0.f;
            for (int j = 0; j < NTOK; j++) {
                float e = __expf(s_S[tid*LDSS + j] - m);
                s_S[tid*LDSS + j] = e;
                sum += e;
            }
            const float inv = 1.f / sum;
            for (int j = 0; j < NTOK; j++) s_S[tid*LDSS + j] *= inv;
        }
        __syncthreads();
        for (int idx = tid; idx < NTOK * 32; idx += 256) {
            const int i = idx >> 5, d = idx & 31;
            float acc = 0.f;
            for (int j = 0; j < NTOK; j++)
                acc += s_S[i*LDSS + j] * bf2f(s_B[j*LDQ + 2*DIMC + h*32 + d]);
            s_A[i*LDA + h*32 + d] = f2bf(acc);
        }
        __syncthreads();
    }

    // ---- P4: xw = O @ (Wp hi+lo) + b (MFMA) -> s_XW [64][LDA] ----
    {
        bf16x8 ao[4][6];
#pragma unroll
        for (int mt = 0; mt < 4; mt++)
#pragma unroll
            for (int kk = 0; kk < 6; kk++)
                ao[mt][kk] = *(const bf16x8*)&s_A[(mt*16 + ar)*LDA + kk*32 + ak];
#pragma unroll
        for (int ntl = 0; ntl < 3; ntl++) {
            const int col = (wv*3 + ntl)*16 + ar;
            const float bias = proj_b[col];
            const u16* wc = Wpt + (size_t)col * 384;
            bf16x8 bh[6], bl[6];
#pragma unroll
            for (int kk = 0; kk < 6; kk++) {
                bh[kk] = *(const bf16x8*)&wc[kk*32 + ak];
                bl[kk] = *(const bf16x8*)&wc[192 + kk*32 + ak];
            }
            f32x4 acc[4];
#pragma unroll
            for (int mt = 0; mt < 4; mt++) acc[mt] = 0;
#pragma unroll
            for (int kk = 0; kk < 6; kk++)
#pragma unroll
                for (int mt = 0; mt < 4; mt++) {
                    acc[mt] = MFMA(ao[mt][kk], bh[kk], acc[mt]);
                    acc[mt] = MFMA(ao[mt][kk], bl[kk], acc[mt]);
                }
#pragma unroll
            for (int mt = 0; mt < 4; mt++)
#pragma unroll
                for (int rg = 0; rg < 4; rg++)
                    s_XW[(mt*16 + rg0 + rg)*LDA + col] = f2bf(acc[mt][rg] + bias);
        }
    }
    __syncthreads();

    // ---- P5: LN2(xw) -> s_A (rows <49; pad rows of s_A remain zero) ----
    for (int t = wv; t < NTOK; t += 4) {
        float v0 = bf2f(s_XW[t*LDA + lane      ]);
        float v1 = bf2f(s_XW[t*LDA + lane + 64 ]);
        float v2 = bf2f(s_XW[t*LDA + lane + 128]);
        float s  = v0 + v1 + v2;
        float s2 = v0*v0 + v1*v1 + v2*v2;
#pragma unroll
        for (int off = 32; off > 0; off >>= 1) {
            s  += __shfl_xor(s,  off);
            s2 += __shfl_xor(s2, off);
        }
        const float mu   = s * (1.f / 192.f);
        const float rstd = rsqrtf(s2 * (1.f / 192.f) - mu * mu + 1e-5f);
        s_A[t*LDA + lane      ] = f2bf((v0-mu)*rstd*g2[lane]     + be2[lane]);
        s_A[t*LDA + lane + 64 ] = f2bf((v1-mu)*rstd*g2[lane+64]  + be2[lane+64]);
        s_A[t*LDA + lane + 128] = f2bf((v2-mu)*rstd*g2[lane+128] + be2[lane+128]);
    }
    __syncthreads();

    // ---- P6: MLP in 4 hidden-chunks of 192 (MFMA); GEMM2 accum in regs ----
    f32x4 accO[3][4];
#pragma unroll
    for (int i = 0; i < 3; i++)
#pragma unroll
        for (int m = 0; m < 4; m++) accO[i][m] = 0;

    for (int cc = 0; cc < 4; cc++) {
        {
            bf16x8 ax[4][6];
#pragma unroll
            for (int mt = 0; mt < 4; mt++)
#pragma unroll
                for (int kk = 0; kk < 6; kk++)
                    ax[mt][kk] = *(const bf16x8*)&s_A[(mt*16 + ar)*LDA + kk*32 + ak];
#pragma unroll
            for (int ntl = 0; ntl < 3; ntl++) {
                const int ncol = (wv*3 + ntl)*16 + ar;
                const int ngl  = cc*192 + ncol;
                const float bias = b1[ngl];
                const u16* wc = W1t + (size_t)ngl * 384;
                bf16x8 bh[6], bl[6];
#pragma unroll
                for (int kk = 0; kk < 6; kk++) {
                    bh[kk] = *(const bf16x8*)&wc[kk*32 + ak];
                    bl[kk] = *(const bf16x8*)&wc[192 + kk*32 + ak];
                }
                f32x4 acc[4];
#pragma unroll
                for (int mt = 0; mt < 4; mt++) acc[mt] = 0;
#pragma unroll
                for (int kk = 0; kk < 6; kk++)
#pragma unroll
                    for (int mt = 0; mt < 4; mt++) {
                        acc[mt] = MFMA(ax[mt][kk], bh[kk], acc[mt]);
                        acc[mt] = MFMA(ax[mt][kk], bl[kk], acc[mt]);
                    }
#pragma unroll
                for (int mt = 0; mt < 4; mt++)
#pragma unroll
                    for (int rg = 0; rg < 4; rg++) {
                        const float z = acc[mt][rg] + bias;
                        const float g = 0.5f * z * (1.f + erff(z * 0.70710678118654752f));
                        s_H[(mt*16 + rg0 + rg)*LDA + ncol] = f2bf(g);
                    }
            }
        }
        __syncthreads();
        {
            bf16x8 ah[4][6];
#pragma unroll
            for (int mt = 0; mt < 4; mt++)
#pragma unroll
                for (int kk = 0; kk < 6; kk++)
                    ah[mt][kk] = *(const bf16x8*)&s_H[(mt*16 + ar)*LDA + kk*32 + ak];
#pragma unroll
            for (int ntl = 0; ntl < 3; ntl++) {
                const int col = (wv*3 + ntl)*16 + ar;
                const u16* wc = W2t + (size_t)col * 1536 + cc*192;
                bf16x8 bh[6], bl[6];
#pragma unroll
                for (int kk = 0; kk < 6; kk++) {
                    bh[kk] = *(const bf16x8*)&wc[kk*32 + ak];
                    bl[kk] = *(const bf16x8*)&wc[768 + kk*32 + ak];
                }
#pragma unroll
                for (int kk = 0; kk < 6; kk++)
#pragma unroll
                    for (int mt = 0; mt < 4; mt++) {
                        accO[ntl][mt] = MFMA(ah[mt][kk], bh[kk], accO[ntl][mt]);
                        accO[ntl][mt] = MFMA(ah[mt][kk], bl[kk], accO[ntl][mt]);
                    }
            }
        }
        __syncthreads();
    }

    // ---- P7: out = accO + b2 + residual(xw), reverse-shift scatter ----
#pragma unroll
    for (int ntl = 0; ntl < 3; ntl++) {
        const int col = (wv*3 + ntl)*16 + ar;
        const float bias = b2[col];
#pragma unroll
        for (int mt = 0; mt < 4; mt++)
#pragma unroll
            for (int rg = 0; rg < 4; rg++) {
                const int row = mt*16 + rg0 + rg;
                if (row < NTOK) {
                    const int pi = row / 7, pj = row - pi * 7;
                    const int di = (wi * WSZ + pi + SSH) % HH;
                    const int dj = (wj * WSZ + pj + SSH) % HH;
                    out[((size_t)b * LTOT + di * HH + dj) * DIMC + col] =
                        accO[ntl][mt][rg] + bias + bf2f(s_XW[row*LDA + col]);
                }
            }
    }
}

// ---------------------------------------------------------------------------
// Fallback: round-2 scalar kernel (known-good), used only if ws too small.
// ---------------------------------------------------------------------------
__global__ __launch_bounds__(256, 1)
void swin_fallback(const float* __restrict__ x,
                   const float* __restrict__ qkv_w, const float* __restrict__ qkv_b,
                   const float* __restrict__ proj_w, const float* __restrict__ proj_b,
                   const float* __restrict__ g1, const float* __restrict__ be1,
                   const float* __restrict__ g2, const float* __restrict__ be2,
                   const float* __restrict__ w1, const float* __restrict__ b1,
                   const float* __restrict__ w2, const float* __restrict__ b2,
                   float* __restrict__ out)
{
    __shared__ __align__(16) u16  s_A[NTOK * DIMC];
    __shared__ __align__(16) u16  s_B[NTOK * 3 * DIMC];
    __shared__ __align__(16) float s_S[NTOK * 52];

    const int wid = blockIdx.x;
    const int b  = wid >> 6;
    const int wi = (wid >> 3) & 7;
    const int wj = wid & 7;
    const int tid  = threadIdx.x;
    const int wave = tid >> 6;
    const int lane = tid & 63;

    for (int t = wave; t < NTOK; t += 4) {
        const int pi = t / 7, pj = t - pi * 7;
        const int si = (wi * WSZ + pi + SSH) % HH;
        const int sj = (wj * WSZ + pj + SSH) % HH;
        const size_t base = ((size_t)b * LTOT + si * HH + sj) * DIMC;
        float v0 = x[base + lane], v1 = x[base + lane + 64], v2 = x[base + lane + 128];
        float s = v0+v1+v2, s2 = v0*v0+v1*v1+v2*v2;
#pragma unroll
        for (int off = 32; off > 0; off >>= 1) { s += __shfl_xor(s, off); s2 += __shfl_xor(s2, off); }
        const float mu = s * (1.f/192.f);
        const float rstd = rsqrtf(s2 * (1.f/192.f) - mu*mu + 1e-5f);
        s_A[t*DIMC + lane      ] = f2bf((v0-mu)*rstd*g1[lane]     + be1[lane]);
        s_A[t*DIMC + lane + 64 ] = f2bf((v1-mu)*rstd*g1[lane+64]  + be1[lane+64]);
        s_A[t*DIMC + lane + 128] = f2bf((v2-mu)*rstd*g1[lane+128] + be1[lane+128]);
    }
    __syncthreads();
    {
        const u32* xn2 = reinterpret_cast<const u32*>(s_A);
        for (int n = tid; n < 3*DIMC; n += 256) {
            const float bias = qkv_b[n];
            for (int t0 = 0; t0 < NTOK; t0 += 16) {
                const int tn = (NTOK - t0) < 16 ? (NTOK - t0) : 16;
                float acc[16];
#pragma unroll
                for (int i = 0; i < 16; i++) acc[i] = 0.f;
                for (int k = 0; k < DIMC; k += 2) {
                    const float wv0 = qkv_w[(size_t)k*(3*DIMC) + n];
                    const float wv1 = qkv_w[(size_t)(k+1)*(3*DIMC) + n];
#pragma unroll
                    for (int i = 0; i < 16; i++)
                        if (i < tn) {
                            u32 u = xn2[((t0+i)*DIMC + k) >> 1];
                            acc[i] += bf2f((u16)u)*wv0 + bf2f((u16)(u>>16))*wv1;
                        }
                }
                for (int i = 0; i < tn; i++) s_B[(t0+i)*(3*DIMC) + n] = f2bf(acc[i] + bias);
            }
        }
    }
    __syncthreads();
    const float scale = 0.1767766952966369f;
    for (int h = 0; h < NHEAD; h++) {
        for (int idx = tid; idx < NTOK*NTOK; idx += 256) {
            const int i = idx / NTOK, j = idx - i*NTOK;
            const u32* qp = reinterpret_cast<const u32*>(&s_B[i*(3*DIMC) + h*32]);
            const u32* kp = reinterpret_cast<const u32*>(&s_B[j*(3*DIMC) + DIMC + h*32]);
            float acc = 0.f;
#pragma unroll
            for (int d = 0; d < 16; d++) {
                const u32 qu = qp[d], ku = kp[d];
                acc += bf2f((u16)qu)*bf2f((u16)ku) + bf2f((u16)(qu>>16))*bf2f((u16)(ku>>16));
            }
            s_S[i*52 + j] = acc * scale;
        }
        __syncthreads();
        if (tid < NTOK) {
            float m = -1e30f;
            for (int j = 0; j < NTOK; j++) m = fmaxf(m, s_S[tid*52 + j]);
            float sum = 0.f;
            for (int j = 0; j < NTOK; j++) { float e = __expf(s_S[tid*52+j]-m); s_S[tid*52+j] = e; sum += e; }
            const float inv = 1.f/sum;
            for (int j = 0; j < NTOK; j++) s_S[tid*52+j] *= inv;
        }
        __syncthreads();
        for (int idx = tid; idx < NTOK*32; idx += 256) {
            const int i = idx >> 5, d = idx & 31;
            float acc = 0.f;
            for (int j = 0; j < NTOK; j++)
                acc += s_S[i*52+j] * bf2f(s_B[j*(3*DIMC) + 2*DIMC + h*32 + d]);
            s_A[i*DIMC + h*32 + d] = f2bf(acc);
        }
        __syncthreads();
    }
    if (tid < DIMC) {
        const int n = tid;
        const float bias = proj_b[n];
        const u32* O2 = reinterpret_cast<const u32*>(s_A);
        for (int t0 = 0; t0 < NTOK; t0 += 16) {
            const int tn = (NTOK - t0) < 16 ? (NTOK - t0) : 16;
            float acc[16];
#pragma unroll
            for (int i = 0; i < 16; i++) acc[i] = 0.f;
            for (int k = 0; k < DIMC; k += 2) {
                const float wv0 = proj_w[k*DIMC + n];
                const float wv1 = proj_w[(k+1)*DIMC + n];
#pragma unroll
                for (int i = 0; i < 16; i++)
                    if (i < tn) {
                        u32 u = O2[((t0+i)*DIMC + k) >> 1];
                        acc[i] += bf2f((u16)u)*wv0 + bf2f((u16)(u>>16))*wv1;
                    }
            }
            for (int i = 0; i < tn; i++) s_B[(t0+i)*DIMC + n] = f2bf(acc[i] + bias);
        }
    }
    __syncthreads();
    for (int t = wave; t < NTOK; t += 4) {
        float v0 = bf2f(s_B[t*DIMC + lane]);
        float v1 = bf2f(s_B[t*DIMC + lane + 64]);
        float v2 = bf2f(s_B[t*DIMC + lane + 128]);
        float s = v0+v1+v2, s2 = v0*v0+v1*v1+v2*v2;
#pragma unroll
        for (int off = 32; off > 0; off >>= 1) { s += __shfl_xor(s, off); s2 += __shfl_xor(s2, off); }
        const float mu = s * (1.f/192.f);
        const float rstd = rsqrtf(s2 * (1.f/192.f) - mu*mu + 1e-5f);
        s_A[t*DIMC + lane      ] = f2bf((v0-mu)*rstd*g2[lane]     + be2[lane]);
        s_A[t*DIMC + lane + 64 ] = f2bf((v1-mu)*rstd*g2[lane+64]  + be2[lane+64]);
        s_A[t*DIMC + lane + 128] = f2bf((v2-mu)*rstd*g2[lane+128] + be2[lane+128]);
    }
    __syncthreads();
    u16* s_h = s_B + NTOK * DIMC;
    for (int tg = 0; tg < 4; tg++) {
        const int tbase = tg * 13;
        const int tcnt = (NTOK - tbase) < 13 ? (NTOK - tbase) : 13;
        {
            const u32* xl2 = reinterpret_cast<const u32*>(s_A);
            for (int n = tid; n < HIDDEN; n += 256) {
                float acc[13];
#pragma unroll
                for (int i = 0; i < 13; i++) acc[i] = 0.f;
                for (int k = 0; k < DIMC; k += 2) {
                    const float wv0 = w1[(size_t)k*HIDDEN + n];
                    const float wv1 = w1[(size_t)(k+1)*HIDDEN + n];
#pragma unroll
                    for (int i = 0; i < 13; i++)
                        if (i < tcnt) {
                            u32 u = xl2[((tbase+i)*DIMC + k) >> 1];
                            acc[i] += bf2f((u16)u)*wv0 + bf2f((u16)(u>>16))*wv1;
                        }
                }
                const float bb = b1[n];
                for (int i = 0; i < tcnt; i++) {
                    const float z = acc[i] + bb;
                    s_h[i*HIDDEN + n] = f2bf(0.5f*z*(1.f + erff(z*0.70710678118f)));
                }
            }
        }
        __syncthreads();
        if (tid < DIMC) {
            const int n = tid;
            const u32* h2 = reinterpret_cast<const u32*>(s_h);
            float acc[13];
#pragma unroll
            for (int i = 0; i < 13; i++) acc[i] = 0.f;
            for (int k = 0; k < HIDDEN; k += 2) {
                const float wv0 = w2[(size_t)k*DIMC + n];
                const float wv1 = w2[(size_t)(k+1)*DIMC + n];
#pragma unroll
                for (int i = 0; i < 13; i++)
                    if (i < tcnt) {
                        u32 u = h2[(i*HIDDEN + k) >> 1];
                        acc[i] += bf2f((u16)u)*wv0 + bf2f((u16)(u>>16))*wv1;
                    }
            }
            const float bb = b2[n];
            for (int i = 0; i < tcnt; i++) {
                const int t = tbase + i;
                const int pi = t / 7, pj = t - pi*7;
                const int di = (wi*WSZ + pi + SSH) % HH;
                const int dj = (wj*WSZ + pj + SSH) % HH;
                out[((size_t)b*LTOT + di*HH + dj)*DIMC + n] = acc[i] + bb + bf2f(s_B[t*DIMC + n]);
            }
        }
        __syncthreads();
    }
}

extern "C" void kernel_launch(void* const* d_in, const int* in_sizes, int n_in,
                              void* d_out, int out_size, void* d_ws, size_t ws_size,
                              hipStream_t stream)
{
    const float* x      = (const float*)d_in[0];
    const float* qkv_w  = (const float*)d_in[1];
    const float* qkv_b  = (const float*)d_in[2];
    const float* proj_w = (const float*)d_in[3];
    const float* proj_b = (const float*)d_in[4];
    const float* g1     = (const float*)d_in[5];
    const float* be1    = (const float*)d_in[6];
    const float* g2     = (const float*)d_in[7];
    const float* be2    = (const float*)d_in[8];
    const float* w1     = (const float*)d_in[9];
    const float* b1     = (const float*)d_in[10];
    const float* w2     = (const float*)d_in[11];
    const float* b2     = (const float*)d_in[12];
    float* out = (float*)d_out;

    if (ws_size >= (size_t)WS_BYTES) {
        cvt_weights<<<256, 256, 0, stream>>>(qkv_w, proj_w, w1, w2, (u16*)d_ws);
        swin_mfma<<<NWIN_T, 256, 0, stream>>>(x, qkv_b, proj_b, g1, be1, g2, be2,
                                              b1, b2, (const u16*)d_ws, out);
    } else {
        swin_fallback<<<NWIN_T, 256, 0, stream>>>(x, qkv_w, qkv_b, proj_w, proj_b,
                                                  g1, be1, g2, be2, w1, b1, w2, b2, out);
    }
}

// Round 6
// 490.425 us; speedup vs baseline: 27.9017x; 2.2557x over previous
//
#include <hip/hip_runtime.h>

typedef unsigned short u16;
typedef unsigned int   u32;
typedef __attribute__((ext_vector_type(8))) short bf16x8;
typedef __attribute__((ext_vector_type(4))) float f32x4;

#define DIMC   192
#define HH     56
#define WSZ    7
#define SSH    3
#define NTOK   49
#define NWIN_T 2048
#define HIDDEN 768
#define LTOT   3136

#define LDA    200    // u16 row stride for [64][<=192] tiles (400B rows, 2-way free)
#define LDSS   68     // dword row stride of S / P region (272B rows, 2-way free)
#define LDPU   136    // u16 view of same region (2*LDSS)
#define LDVT   72     // u16 row stride of V^T

// ws layout (u16 elems): per weight col, [K hi | K lo] contiguous (stride 2K)
#define OFF_QKV 0                         // 576 cols * 384
#define OFF_PW  221184                    // + 192 * 384
#define OFF_W1  294912                    // + 768 * 384
#define OFF_W2  589824                    // + 192 * 1536
#define WS_ELEMS 884736
#define WS_BYTES (WS_ELEMS * 2)

#define MFMA(a,b,c) __builtin_amdgcn_mfma_f32_16x16x32_bf16((a),(b),(c),0,0,0)

__device__ __forceinline__ float bf2f(u16 u) {
    union { u32 i; float f; } v; v.i = ((u32)u) << 16; return v.f;
}
__device__ __forceinline__ u16 f2bf(float f) {
    union { float ff; u32 i; } v; v.ff = f;
    u32 x = v.i;
    return (u16)((x + 0x7FFFu + ((x >> 16) & 1u)) >> 16);  // RNE
}
__device__ __forceinline__ void split_store(u16* hi, u16* lo, float w) {
    u16 h = f2bf(w);
    *hi = h;
    *lo = f2bf(w - bf2f(h));
}

// ---------------------------------------------------------------------------
// Prep: fp32 [K][N] -> split bf16 W^T stored [N][ hi[0:K] | lo[0:K] ].
// ---------------------------------------------------------------------------
__global__ void cvt_weights(const float* __restrict__ qkv_w,
                            const float* __restrict__ proj_w,
                            const float* __restrict__ w1,
                            const float* __restrict__ w2,
                            u16* __restrict__ ws)
{
    const int idx = blockIdx.x * blockDim.x + threadIdx.x;
    const int stride = gridDim.x * blockDim.x;
    for (int i = idx; i < 110592; i += stride) {        // qkv [192][576]
        int k = i / 576, n = i - k * 576;
        u16* base = ws + OFF_QKV + (size_t)n * 384;
        split_store(base + k, base + 192 + k, qkv_w[i]);
    }
    for (int i = idx; i < 36864; i += stride) {         // proj [192][192]
        int k = i / 192, n = i - k * 192;
        u16* base = ws + OFF_PW + (size_t)n * 384;
        split_store(base + k, base + 192 + k, proj_w[i]);
    }
    for (int i = idx; i < 147456; i += stride) {        // w1 [192][768]
        int k = i / 768, n = i - k * 768;
        u16* base = ws + OFF_W1 + (size_t)n * 384;
        split_store(base + k, base + 192 + k, w1[i]);
    }
    for (int i = idx; i < 147456; i += stride) {        // w2 [768][192]
        int k = i / 192, n = i - k * 192;
        u16* base = ws + OFF_W2 + (size_t)n * 1536;
        split_store(base + k, base + 768 + k, w2[i]);
    }
}

// ---------------------------------------------------------------------------
// Fully-MFMA fused Swin block. 4 waves/block, 2 blocks/CU (76.8 KB LDS).
// Attention: per-2-head QKV groups; MFMA QK^T; wave-parallel fp32 softmax;
// MFMA PV with split hi/lo P. O tiles live in 12 named VGPR accumulators.
// ---------------------------------------------------------------------------

// QKV for heads 2G, 2G+1 -> s_Q cols [0:64)=Q [64:128)=K [128:192)=V
#define QKV_GROUP(G) { \
    _Pragma("unroll") \
    for (int tl = 0; tl < 3; tl++) { \
        const int tt = wv*3 + tl; \
        const int section = tt >> 2, idxq = tt & 3; \
        const int gcol = section*192 + (G)*64 + idxq*16 + ar; \
        const int lcol = section*64 + idxq*16 + ar; \
        const float bias = qkv_b[gcol]; \
        const u16* wc = Wqkvt + (size_t)gcol * 384; \
        f32x4 acc[4]; \
        _Pragma("unroll") for (int mt = 0; mt < 4; mt++) acc[mt] = 0; \
        _Pragma("unroll") \
        for (int kk = 0; kk < 6; kk++) { \
            bf16x8 bh = *(const bf16x8*)&wc[kk*32 + ak]; \
            bf16x8 bl = *(const bf16x8*)&wc[192 + kk*32 + ak]; \
            _Pragma("unroll") \
            for (int mt = 0; mt < 4; mt++) { \
                bf16x8 a = *(const bf16x8*)&s_A[(mt*16 + ar)*LDA + kk*32 + ak]; \
                acc[mt] = MFMA(a, bh, acc[mt]); \
                acc[mt] = MFMA(a, bl, acc[mt]); \
            } \
        } \
        _Pragma("unroll") \
        for (int mt = 0; mt < 4; mt++) \
            _Pragma("unroll") \
            for (int rg = 0; rg < 4; rg++) \
                s_Q[(mt*16 + rg0 + rg)*LDA + lcol] = f2bf(acc[mt][rg] + bias); \
    } }

// one head (HL = 0/1 within group): QK^T -> softmax (P hi/lo) -> PV -> O0,O1
#define ATTN_HEAD(HL, O0, O1) { \
    { /* S = scale * Q K^T ; wave wv owns col-tile jt = wv */ \
        const int jt = wv; \
        bf16x8 bk = *(const bf16x8*)&s_Q[(jt*16 + ar)*LDA + 64 + (HL)*32 + ak]; \
        _Pragma("unroll") \
        for (int mt = 0; mt < 4; mt++) { \
            bf16x8 aq = *(const bf16x8*)&s_Q[(mt*16 + ar)*LDA + (HL)*32 + ak]; \
            f32x4 sa; sa = 0; \
            sa = MFMA(aq, bk, sa); \
            _Pragma("unroll") \
            for (int rg = 0; rg < 4; rg++) \
                Sf[(mt*16 + rg0 + rg)*LDSS + jt*16 + ar] = sa[rg] * scale; \
        } } \
    __syncthreads(); \
    { /* softmax rows (4 lanes/row, regs only) -> P hi|lo over dead S; Vt fill */ \
        const int row = tid >> 2, sub = tid & 3; \
        if (row < NTOK) { \
            float e[16]; float m = -1e30f; \
            _Pragma("unroll") \
            for (int i = 0; i < 16; i++) { \
                const int j = sub + 4*i; \
                e[i] = (j < NTOK) ? Sf[row*LDSS + j] : -1e30f; \
                m = fmaxf(m, e[i]); \
            } \
            m = fmaxf(m, __shfl_xor(m, 1)); \
            m = fmaxf(m, __shfl_xor(m, 2)); \
            float sum = 0.f; \
            _Pragma("unroll") \
            for (int i = 0; i < 16; i++) { e[i] = __expf(e[i] - m); sum += e[i]; } \
            sum += __shfl_xor(sum, 1); \
            sum += __shfl_xor(sum, 2); \
            const float inv = 1.f / sum; \
            _Pragma("unroll") \
            for (int i = 0; i < 16; i++) { \
                const int j = sub + 4*i; \
                const float p = e[i] * inv;   /* 0 for j>=49 -> pad cols zeroed */ \
                const u16 hb = f2bf(p); \
                PU[row*LDPU + j] = hb; \
                PU[row*LDPU + 64 + j] = f2bf(p - bf2f(hb)); \
            } \
        } \
        for (int i2 = tid; i2 < 2048; i2 += 256) { \
            const int d = i2 & 31, j = i2 >> 5; \
            Vt[d*LDVT + j] = (j < NTOK) ? s_Q[j*LDA + 128 + (HL)*32 + d] : (u16)0; \
        } } \
    __syncthreads(); \
    { /* O = (Phi+Plo) @ V : 8 tiles over 4 waves, 2 per wave */ \
        const int dcol = (wv & 1)*16 + ar; \
        const int mtb = (wv >> 1) << 1; \
        f32x4 accv; \
        accv = 0; \
        _Pragma("unroll") \
        for (int kk = 0; kk < 2; kk++) { \
            bf16x8 ph = *(const bf16x8*)&PU[((mtb+0)*16 + ar)*LDPU + kk*32 + ak]; \
            bf16x8 pl = *(const bf16x8*)&PU[((mtb+0)*16 + ar)*LDPU + 64 + kk*32 + ak]; \
            bf16x8 bv = *(const bf16x8*)&Vt[dcol*LDVT + kk*32 + ak]; \
            accv = MFMA(ph, bv, accv); \
            accv = MFMA(pl, bv, accv); \
        } \
        O0 = accv; \
        accv = 0; \
        _Pragma("unroll") \
        for (int kk = 0; kk < 2; kk++) { \
            bf16x8 ph = *(const bf16x8*)&PU[((mtb+1)*16 + ar)*LDPU + kk*32 + ak]; \
            bf16x8 pl = *(const bf16x8*)&PU[((mtb+1)*16 + ar)*LDPU + 64 + kk*32 + ak]; \
            bf16x8 bv = *(const bf16x8*)&Vt[dcol*LDVT + kk*32 + ak]; \
            accv = MFMA(ph, bv, accv); \
            accv = MFMA(pl, bv, accv); \
        } \
        O1 = accv; } \
    __syncthreads(); }

#define OSTORE(HEADIDX, OV0, OV1) { \
    const int col = (HEADIDX)*32 + (wv & 1)*16 + ar; \
    const int mtb = (wv >> 1) << 1; \
    _Pragma("unroll") \
    for (int rg = 0; rg < 4; rg++) { \
        s_A[((mtb+0)*16 + rg0 + rg)*LDA + col] = f2bf(OV0[rg]); \
        s_A[((mtb+1)*16 + rg0 + rg)*LDA + col] = f2bf(OV1[rg]); \
    } }

__global__ __launch_bounds__(256, 2)
void swin_mfma(const float* __restrict__ x,
               const float* __restrict__ qkv_b, const float* __restrict__ proj_b,
               const float* __restrict__ g1, const float* __restrict__ be1,
               const float* __restrict__ g2, const float* __restrict__ be2,
               const float* __restrict__ b1, const float* __restrict__ b2,
               const u16* __restrict__ wsw, float* __restrict__ out)
{
    __shared__ __align__(16) u16 s_A[64 * LDA];    // xn -> O -> xln (25.6 KB)
    __shared__ __align__(16) u16 s_Q[64 * LDA];    // qkv group -> xw (25.6 KB)
    __shared__ __align__(16) u16 s_R3[64 * LDA];   // S/P + Vt -> h   (25.6 KB)

    float* const Sf  = (float*)s_R3;               // [64][68] f32
    u16*  const PU   = s_R3;                       // [64][136] u16 (same bytes)
    u16*  const Vt   = s_R3 + 64 * LDSS * 2;       // [32][72] u16
    u16*  const s_H  = s_R3;                       // MLP hidden chunk
    u16*  const s_XW = s_Q;                        // xw after attention

    const int wid = blockIdx.x;
    const int b  = wid >> 6;
    const int wi = (wid >> 3) & 7;
    const int wj = wid & 7;
    const int tid  = threadIdx.x;
    const int wv   = tid >> 6;
    const int lane = tid & 63;
    const int ar   = lane & 15;
    const int ak   = (lane >> 4) << 3;
    const int rg0  = (lane >> 4) << 2;
    const float scale = 0.1767766952966369f;   // 1/sqrt(32)

    const u16* Wqkvt = wsw + OFF_QKV;
    const u16* Wpt   = wsw + OFF_PW;
    const u16* W1t   = wsw + OFF_W1;
    const u16* W2t   = wsw + OFF_W2;

    // ---- P1: gather (shift -SSH) + LN1 -> s_A; pad rows 49..63 zeroed ----
    for (int t = wv; t < 64; t += 4) {
        if (t < NTOK) {
            const int pi = t / 7, pj = t - pi * 7;
            const int si = (wi * WSZ + pi + SSH) % HH;
            const int sj = (wj * WSZ + pj + SSH) % HH;
            const float* src = x + ((size_t)b * LTOT + si * HH + sj) * DIMC;
            float v0 = src[lane], v1 = src[lane + 64], v2 = src[lane + 128];
            float s  = v0 + v1 + v2;
            float s2 = v0 * v0 + v1 * v1 + v2 * v2;
#pragma unroll
            for (int off = 32; off > 0; off >>= 1) {
                s  += __shfl_xor(s,  off);
                s2 += __shfl_xor(s2, off);
            }
            const float mu   = s * (1.f / 192.f);
            const float rstd = rsqrtf(s2 * (1.f / 192.f) - mu * mu + 1e-5f);
            s_A[t*LDA + lane      ] = f2bf((v0-mu)*rstd*g1[lane]     + be1[lane]);
            s_A[t*LDA + lane + 64 ] = f2bf((v1-mu)*rstd*g1[lane+64]  + be1[lane+64]);
            s_A[t*LDA + lane + 128] = f2bf((v2-mu)*rstd*g1[lane+128] + be1[lane+128]);
        } else {
            s_A[t*LDA + lane] = 0; s_A[t*LDA + lane + 64] = 0; s_A[t*LDA + lane + 128] = 0;
        }
    }
    __syncthreads();

    // ---- attention: 3 groups x 2 heads, O in 12 named accumulators ----
    f32x4 o0, o1, o2, o3, o4, o5, o6, o7, o8, o9, o10, o11;

    QKV_GROUP(0) __syncthreads();
    ATTN_HEAD(0, o0, o1)
    ATTN_HEAD(1, o2, o3)
    QKV_GROUP(1) __syncthreads();
    ATTN_HEAD(0, o4, o5)
    ATTN_HEAD(1, o6, o7)
    QKV_GROUP(2) __syncthreads();
    ATTN_HEAD(0, o8, o9)
    ATTN_HEAD(1, o10, o11)

    // xn fully consumed; O -> s_A
    OSTORE(0, o0, o1)  OSTORE(1, o2, o3)  OSTORE(2, o4, o5)
    OSTORE(3, o6, o7)  OSTORE(4, o8, o9)  OSTORE(5, o10, o11)
    __syncthreads();

    // ---- P4: xw = O @ (Wp hi+lo) + b (MFMA) -> s_XW ----
    {
        bf16x8 ao[4][6];
#pragma unroll
        for (int mt = 0; mt < 4; mt++)
#pragma unroll
            for (int kk = 0; kk < 6; kk++)
                ao[mt][kk] = *(const bf16x8*)&s_A[(mt*16 + ar)*LDA + kk*32 + ak];
#pragma unroll
        for (int ntl = 0; ntl < 3; ntl++) {
            const int col = (wv*3 + ntl)*16 + ar;
            const float bias = proj_b[col];
            const u16* wc = Wpt + (size_t)col * 384;
            bf16x8 bh[6], bl[6];
#pragma unroll
            for (int kk = 0; kk < 6; kk++) {
                bh[kk] = *(const bf16x8*)&wc[kk*32 + ak];
                bl[kk] = *(const bf16x8*)&wc[192 + kk*32 + ak];
            }
            f32x4 acc[4];
#pragma unroll
            for (int mt = 0; mt < 4; mt++) acc[mt] = 0;
#pragma unroll
            for (int kk = 0; kk < 6; kk++)
#pragma unroll
                for (int mt = 0; mt < 4; mt++) {
                    acc[mt] = MFMA(ao[mt][kk], bh[kk], acc[mt]);
                    acc[mt] = MFMA(ao[mt][kk], bl[kk], acc[mt]);
                }
#pragma unroll
            for (int mt = 0; mt < 4; mt++)
#pragma unroll
                for (int rg = 0; rg < 4; rg++)
                    s_XW[(mt*16 + rg0 + rg)*LDA + col] = f2bf(acc[mt][rg] + bias);
        }
    }
    __syncthreads();

    // ---- P5: LN2(xw) -> s_A rows <49 ----
    for (int t = wv; t < NTOK; t += 4) {
        float v0 = bf2f(s_XW[t*LDA + lane      ]);
        float v1 = bf2f(s_XW[t*LDA + lane + 64 ]);
        float v2 = bf2f(s_XW[t*LDA + lane + 128]);
        float s  = v0 + v1 + v2;
        float s2 = v0*v0 + v1*v1 + v2*v2;
#pragma unroll
        for (int off = 32; off > 0; off >>= 1) {
            s  += __shfl_xor(s,  off);
            s2 += __shfl_xor(s2, off);
        }
        const float mu   = s * (1.f / 192.f);
        const float rstd = rsqrtf(s2 * (1.f / 192.f) - mu * mu + 1e-5f);
        s_A[t*LDA + lane      ] = f2bf((v0-mu)*rstd*g2[lane]     + be2[lane]);
        s_A[t*LDA + lane + 64 ] = f2bf((v1-mu)*rstd*g2[lane+64]  + be2[lane+64]);
        s_A[t*LDA + lane + 128] = f2bf((v2-mu)*rstd*g2[lane+128] + be2[lane+128]);
    }
    __syncthreads();

    // ---- P6: MLP in 4 hidden-chunks of 192 (MFMA); GEMM2 accum in regs ----
    f32x4 accO[3][4];
#pragma unroll
    for (int i = 0; i < 3; i++)
#pragma unroll
        for (int m = 0; m < 4; m++) accO[i][m] = 0;

    for (int cc = 0; cc < 4; cc++) {
        {
            bf16x8 ax[4][6];
#pragma unroll
            for (int mt = 0; mt < 4; mt++)
#pragma unroll
                for (int kk = 0; kk < 6; kk++)
                    ax[mt][kk] = *(const bf16x8*)&s_A[(mt*16 + ar)*LDA + kk*32 + ak];
#pragma unroll
            for (int ntl = 0; ntl < 3; ntl++) {
                const int ncol = (wv*3 + ntl)*16 + ar;
                const int ngl  = cc*192 + ncol;
                const float bias = b1[ngl];
                const u16* wc = W1t + (size_t)ngl * 384;
                bf16x8 bh[6], bl[6];
#pragma unroll
                for (int kk = 0; kk < 6; kk++) {
                    bh[kk] = *(const bf16x8*)&wc[kk*32 + ak];
                    bl[kk] = *(const bf16x8*)&wc[192 + kk*32 + ak];
                }
                f32x4 acc[4];
#pragma unroll
                for (int mt = 0; mt < 4; mt++) acc[mt] = 0;
#pragma unroll
                for (int kk = 0; kk < 6; kk++)
#pragma unroll
                    for (int mt = 0; mt < 4; mt++) {
                        acc[mt] = MFMA(ax[mt][kk], bh[kk], acc[mt]);
                        acc[mt] = MFMA(ax[mt][kk], bl[kk], acc[mt]);
                    }
#pragma unroll
                for (int mt = 0; mt < 4; mt++)
#pragma unroll
                    for (int rg = 0; rg < 4; rg++) {
                        const float z = acc[mt][rg] + bias;
                        const float g = 0.5f * z * (1.f + erff(z * 0.70710678118654752f));
                        s_H[(mt*16 + rg0 + rg)*LDA + ncol] = f2bf(g);
                    }
            }
        }
        __syncthreads();
        {
            bf16x8 ah[4][6];
#pragma unroll
            for (int mt = 0; mt < 4; mt++)
#pragma unroll
                for (int kk = 0; kk < 6; kk++)
                    ah[mt][kk] = *(const bf16x8*)&s_H[(mt*16 + ar)*LDA + kk*32 + ak];
#pragma unroll
            for (int ntl = 0; ntl < 3; ntl++) {
                const int col = (wv*3 + ntl)*16 + ar;
                const u16* wc = W2t + (size_t)col * 1536 + cc*192;
                bf16x8 bh[6], bl[6];
#pragma unroll
                for (int kk = 0; kk < 6; kk++) {
                    bh[kk] = *(const bf16x8*)&wc[kk*32 + ak];
                    bl[kk] = *(const bf16x8*)&wc[768 + kk*32 + ak];
                }
#pragma unroll
                for (int kk = 0; kk < 6; kk++)
#pragma unroll
                    for (int mt = 0; mt < 4; mt++) {
                        accO[ntl][mt] = MFMA(ah[mt][kk], bh[kk], accO[ntl][mt]);
                        accO[ntl][mt] = MFMA(ah[mt][kk], bl[kk], accO[ntl][mt]);
                    }
            }
        }
        __syncthreads();
    }

    // ---- P7: out = accO + b2 + residual(xw), reverse-shift scatter ----
#pragma unroll
    for (int ntl = 0; ntl < 3; ntl++) {
        const int col = (wv*3 + ntl)*16 + ar;
        const float bias = b2[col];
#pragma unroll
        for (int mt = 0; mt < 4; mt++)
#pragma unroll
            for (int rg = 0; rg < 4; rg++) {
                const int row = mt*16 + rg0 + rg;
                if (row < NTOK) {
                    const int pi = row / 7, pj = row - pi * 7;
                    const int di = (wi * WSZ + pi + SSH) % HH;
                    const int dj = (wj * WSZ + pj + SSH) % HH;
                    out[((size_t)b * LTOT + di * HH + dj) * DIMC + col] =
                        accO[ntl][mt][rg] + bias + bf2f(s_XW[row*LDA + col]);
                }
            }
    }
}

// ---------------------------------------------------------------------------
// Fallback: round-2 scalar kernel (known-good), used only if ws too small.
// ---------------------------------------------------------------------------
__global__ __launch_bounds__(256, 1)
void swin_fallback(const float* __restrict__ x,
                   const float* __restrict__ qkv_w, const float* __restrict__ qkv_b,
                   const float* __restrict__ proj_w, const float* __restrict__ proj_b,
                   const float* __restrict__ g1, const float* __restrict__ be1,
                   const float* __restrict__ g2, const float* __restrict__ be2,
                   const float* __restrict__ w1, const float* __restrict__ b1,
                   const float* __restrict__ w2, const float* __restrict__ b2,
                   float* __restrict__ out)
{
    __shared__ __align__(16) u16  s_A[NTOK * DIMC];
    __shared__ __align__(16) u16  s_B[NTOK * 3 * DIMC];
    __shared__ __align__(16) float s_S[NTOK * 52];

    const int wid = blockIdx.x;
    const int b  = wid >> 6;
    const int wi = (wid >> 3) & 7;
    const int wj = wid & 7;
    const int tid  = threadIdx.x;
    const int wave = tid >> 6;
    const int lane = tid & 63;

    for (int t = wave; t < NTOK; t += 4) {
        const int pi = t / 7, pj = t - pi * 7;
        const int si = (wi * WSZ + pi + SSH) % HH;
        const int sj = (wj * WSZ + pj + SSH) % HH;
        const size_t base = ((size_t)b * LTOT + si * HH + sj) * DIMC;
        float v0 = x[base + lane], v1 = x[base + lane + 64], v2 = x[base + lane + 128];
        float s = v0+v1+v2, s2 = v0*v0+v1*v1+v2*v2;
#pragma unroll
        for (int off = 32; off > 0; off >>= 1) { s += __shfl_xor(s, off); s2 += __shfl_xor(s2, off); }
        const float mu = s * (1.f/192.f);
        const float rstd = rsqrtf(s2 * (1.f/192.f) - mu*mu + 1e-5f);
        s_A[t*DIMC + lane      ] = f2bf((v0-mu)*rstd*g1[lane]     + be1[lane]);
        s_A[t*DIMC + lane + 64 ] = f2bf((v1-mu)*rstd*g1[lane+64]  + be1[lane+64]);
        s_A[t*DIMC + lane + 128] = f2bf((v2-mu)*rstd*g1[lane+128] + be1[lane+128]);
    }
    __syncthreads();
    {
        const u32* xn2 = reinterpret_cast<const u32*>(s_A);
        for (int n = tid; n < 3*DIMC; n += 256) {
            const float bias = qkv_b[n];
            for (int t0 = 0; t0 < NTOK; t0 += 16) {
                const int tn = (NTOK - t0) < 16 ? (NTOK - t0) : 16;
                float acc[16];
#pragma unroll
                for (int i = 0; i < 16; i++) acc[i] = 0.f;
                for (int k = 0; k < DIMC; k += 2) {
                    const float wv0 = qkv_w[(size_t)k*(3*DIMC) + n];
                    const float wv1 = qkv_w[(size_t)(k+1)*(3*DIMC) + n];
#pragma unroll
                    for (int i = 0; i < 16; i++)
                        if (i < tn) {
                            u32 u = xn2[((t0+i)*DIMC + k) >> 1];
                            acc[i] += bf2f((u16)u)*wv0 + bf2f((u16)(u>>16))*wv1;
                        }
                }
                for (int i = 0; i < tn; i++) s_B[(t0+i)*(3*DIMC) + n] = f2bf(acc[i] + bias);
            }
        }
    }
    __syncthreads();
    const float scale = 0.1767766952966369f;
    for (int h = 0; h < 6; h++) {
        for (int idx = tid; idx < NTOK*NTOK; idx += 256) {
            const int i = idx / NTOK, j = idx - i*NTOK;
            const u32* qp = reinterpret_cast<const u32*>(&s_B[i*(3*DIMC) + h*32]);
            const u32* kp = reinterpret_cast<const u32*>(&s_B[j*(3*DIMC) + DIMC + h*32]);
            float acc = 0.f;
#pragma unroll
            for (int d = 0; d < 16; d++) {
                const u32 qu = qp[d], ku = kp[d];
                acc += bf2f((u16)qu)*bf2f((u16)ku) + bf2f((u16)(qu>>16))*bf2f((u16)(ku>>16));
            }
            s_S[i*52 + j] = acc * scale;
        }
        __syncthreads();
        if (tid < NTOK) {
            float m = -1e30f;
            for (int j = 0; j < NTOK; j++) m = fmaxf(m, s_S[tid*52 + j]);
            float sum = 0.f;
            for (int j = 0; j < NTOK; j++) { float e = __expf(s_S[tid*52+j]-m); s_S[tid*52+j] = e; sum += e; }
            const float inv = 1.f/sum;
            for (int j = 0; j < NTOK; j++) s_S[tid*52+j] *= inv;
        }
        __syncthreads();
        for (int idx = tid; idx < NTOK*32; idx += 256) {
            const int i = idx >> 5, d = idx & 31;
            float acc = 0.f;
            for (int j = 0; j < NTOK; j++)
                acc += s_S[i*52+j] * bf2f(s_B[j*(3*DIMC) + 2*DIMC + h*32 + d]);
            s_A[i*DIMC + h*32 + d] = f2bf(acc);
        }
        __syncthreads();
    }
    if (tid < DIMC) {
        const int n = tid;
        const float bias = proj_b[n];
        const u32* O2 = reinterpret_cast<const u32*>(s_A);
        for (int t0 = 0; t0 < NTOK; t0 += 16) {
            const int tn = (NTOK - t0) < 16 ? (NTOK - t0) : 16;
            float acc[16];
#pragma unroll
            for (int i = 0; i < 16; i++) acc[i] = 0.f;
            for (int k = 0; k < DIMC; k += 2) {
                const float wv0 = proj_w[k*DIMC + n];
                const float wv1 = proj_w[(k+1)*DIMC + n];
#pragma unroll
                for (int i = 0; i < 16; i++)
                    if (i < tn) {
                        u32 u = O2[((t0+i)*DIMC + k) >> 1];
                        acc[i] += bf2f((u16)u)*wv0 + bf2f((u16)(u>>16))*wv1;
                    }
            }
            for (int i = 0; i < tn; i++) s_B[(t0+i)*DIMC + n] = f2bf(acc[i] + bias);
        }
    }
    __syncthreads();
    for (int t = wave; t < NTOK; t += 4) {
        float v0 = bf2f(s_B[t*DIMC + lane]);
        float v1 = bf2f(s_B[t*DIMC + lane + 64]);
        float v2 = bf2f(s_B[t*DIMC + lane + 128]);
        float s = v0+v1+v2, s2 = v0*v0+v1*v1+v2*v2;
#pragma unroll
        for (int off = 32; off > 0; off >>= 1) { s += __shfl_xor(s, off); s2 += __shfl_xor(s2, off); }
        const float mu = s * (1.f/192.f);
        const float rstd = rsqrtf(s2 * (1.f/192.f) - mu*mu + 1e-5f);
        s_A[t*DIMC + lane      ] = f2bf((v0-mu)*rstd*g2[lane]     + be2[lane]);
        s_A[t*DIMC + lane + 64 ] = f2bf((v1-mu)*rstd*g2[lane+64]  + be2[lane+64]);
        s_A[t*DIMC + lane + 128] = f2bf((v2-mu)*rstd*g2[lane+128] + be2[lane+128]);
    }
    __syncthreads();
    u16* s_h = s_B + NTOK * DIMC;
    for (int tg = 0; tg < 4; tg++) {
        const int tbase = tg * 13;
        const int tcnt = (NTOK - tbase) < 13 ? (NTOK - tbase) : 13;
        {
            const u32* xl2 = reinterpret_cast<const u32*>(s_A);
            for (int n = tid; n < HIDDEN; n += 256) {
                float acc[13];
#pragma unroll
                for (int i = 0; i < 13; i++) acc[i] = 0.f;
                for (int k = 0; k < DIMC; k += 2) {
                    const float wv0 = w1[(size_t)k*HIDDEN + n];
                    const float wv1 = w1[(size_t)(k+1)*HIDDEN + n];
#pragma unroll
                    for (int i = 0; i < 13; i++)
                        if (i < tcnt) {
                            u32 u = xl2[((tbase+i)*DIMC + k) >> 1];
                            acc[i] += bf2f((u16)u)*wv0 + bf2f((u16)(u>>16))*wv1;
                        }
                }
                const float bb = b1[n];
                for (int i = 0; i < tcnt; i++) {
                    const float z = acc[i] + bb;
                    s_h[i*HIDDEN + n] = f2bf(0.5f*z*(1.f + erff(z*0.70710678118f)));
                }
            }
        }
        __syncthreads();
        if (tid < DIMC) {
            const int n = tid;
            const u32* h2 = reinterpret_cast<const u32*>(s_h);
            float acc[13];
#pragma unroll
            for (int i = 0; i < 13; i++) acc[i] = 0.f;
            for (int k = 0; k < HIDDEN; k += 2) {
                const float wv0 = w2[(size_t)k*DIMC + n];
                const float wv1 = w2[(size_t)(k+1)*DIMC + n];
#pragma unroll
                for (int i = 0; i < 13; i++)
                    if (i < tcnt) {
                        u32 u = h2[(i*HIDDEN + k) >> 1];
                        acc[i] += bf2f((u16)u)*wv0 + bf2f((u16)(u>>16))*wv1;
                    }
            }
            const float bb = b2[n];
            for (int i = 0; i < tcnt; i++) {
                const int t = tbase + i;
                const int pi = t / 7, pj = t - pi*7;
                const int di = (wi*WSZ + pi + SSH) % HH;
                const int dj = (wj*WSZ + pj + SSH) % HH;
                out[((size_t)b*LTOT + di*HH + dj)*DIMC + n] = acc[i] + bb + bf2f(s_B[t*DIMC + n]);
            }
        }
        __syncthreads();
    }
}

extern "C" void kernel_launch(void* const* d_in, const int* in_sizes, int n_in,
                              void* d_out, int out_size, void* d_ws, size_t ws_size,
                              hipStream_t stream)
{
    const float* x      = (const float*)d_in[0];
    const float* qkv_w  = (const float*)d_in[1];
    const float* qkv_b  = (const float*)d_in[2];
    const float* proj_w = (const float*)d_in[3];
    const float* proj_b = (const float*)d_in[4];
    const float* g1     = (const float*)d_in[5];
    const float* be1    = (const float*)d_in[6];
    const float* g2     = (const float*)d_in[7];
    const float* be2    = (const float*)d_in[8];
    const float* w1     = (const float*)d_in[9];
    const float* b1     = (const float*)d_in[10];
    const float* w2     = (const float*)d_in[11];
    const float* b2     = (const float*)d_in[12];
    float* out = (float*)d_out;

    if (ws_size >= (size_t)WS_BYTES) {
        cvt_weights<<<256, 256, 0, stream>>>(qkv_w, proj_w, w1, w2, (u16*)d_ws);
        swin_mfma<<<NWIN_T, 256, 0, stream>>>(x, qkv_b, proj_b, g1, be1, g2, be2,
                                              b1, b2, (const u16*)d_ws, out);
    } else {
        swin_fallback<<<NWIN_T, 256, 0, stream>>>(x, qkv_w, qkv_b, proj_w, proj_b,
                                                  g1, be1, g2, be2, w1, b1, w2, b2, out);
    }
}

// Round 7
// 487.602 us; speedup vs baseline: 28.0632x; 1.0058x over previous
//
#include <hip/hip_runtime.h>

typedef unsigned short u16;
typedef unsigned int   u32;
typedef __attribute__((ext_vector_type(8))) short bf16x8;
typedef __attribute__((ext_vector_type(4))) float f32x4;

#define DIMC   192
#define HH     56
#define WSZ    7
#define SSH    3
#define NTOK   49
#define NWIN_T 2048
#define HIDDEN 768
#define LTOT   3136

#define LDA    200    // u16 row stride, [128][<=192] tiles
#define LDSS   68     // f32 row stride of S
#define LDPU   136    // u16 view (2*LDSS): hi cols 0-63, lo cols 64-127
#define LDVT   72     // u16 row stride of V^T
#define LDH    136    // u16 row stride of H chunk [128][128]

// ws layout (u16 elems): per weight col, [K hi | K lo] contiguous (stride 2K)
#define OFF_QKV 0                         // 576 cols * 384
#define OFF_PW  221184                    // + 192 * 384
#define OFF_W1  294912                    // + 768 * 384
#define OFF_W2  589824                    // + 192 * 1536
#define WS_ELEMS 884736
#define WS_BYTES (WS_ELEMS * 2)

#define MFMA(a,b,c) __builtin_amdgcn_mfma_f32_16x16x32_bf16((a),(b),(c),0,0,0)

__device__ __forceinline__ float bf2f(u16 u) {
    union { u32 i; float f; } v; v.i = ((u32)u) << 16; return v.f;
}
__device__ __forceinline__ u16 f2bf(float f) {
    union { float ff; u32 i; } v; v.ff = f;
    u32 x = v.i;
    return (u16)((x + 0x7FFFu + ((x >> 16) & 1u)) >> 16);  // RNE
}
__device__ __forceinline__ void split_store(u16* hi, u16* lo, float w) {
    u16 h = f2bf(w);
    *hi = h;
    *lo = f2bf(w - bf2f(h));
}

// ---------------------------------------------------------------------------
// Prep: fp32 [K][N] -> split bf16 W^T stored [N][ hi[0:K] | lo[0:K] ].
// ---------------------------------------------------------------------------
__global__ void cvt_weights(const float* __restrict__ qkv_w,
                            const float* __restrict__ proj_w,
                            const float* __restrict__ w1,
                            const float* __restrict__ w2,
                            u16* __restrict__ ws)
{
    const int idx = blockIdx.x * blockDim.x + threadIdx.x;
    const int stride = gridDim.x * blockDim.x;
    for (int i = idx; i < 110592; i += stride) {        // qkv [192][576]
        int k = i / 576, n = i - k * 576;
        u16* base = ws + OFF_QKV + (size_t)n * 384;
        split_store(base + k, base + 192 + k, qkv_w[i]);
    }
    for (int i = idx; i < 36864; i += stride) {         // proj [192][192]
        int k = i / 192, n = i - k * 192;
        u16* base = ws + OFF_PW + (size_t)n * 384;
        split_store(base + k, base + 192 + k, proj_w[i]);
    }
    for (int i = idx; i < 147456; i += stride) {        // w1 [192][768]
        int k = i / 768, n = i - k * 768;
        u16* base = ws + OFF_W1 + (size_t)n * 384;
        split_store(base + k, base + 192 + k, w1[i]);
    }
    for (int i = idx; i < 147456; i += stride) {        // w2 [768][192]
        int k = i / 192, n = i - k * 192;
        u16* base = ws + OFF_W2 + (size_t)n * 1536;
        split_store(base + k, base + 768 + k, w2[i]);
    }
}

// ---------------------------------------------------------------------------
// Fused Swin block: 2 windows per 512-thread block (M=128 weight GEMMs).
// Waves 0-3 -> window A, 4-7 -> window B for attention; all 8 waves share
// M=128 row-tiles in QKV/proj/MLP (2x MFMA per weight-fragment load).
// ---------------------------------------------------------------------------
__global__ __launch_bounds__(512, 2)
void swin_mfma(const float* __restrict__ x,
               const float* __restrict__ qkv_b, const float* __restrict__ proj_b,
               const float* __restrict__ g1, const float* __restrict__ be1,
               const float* __restrict__ g2, const float* __restrict__ be2,
               const float* __restrict__ b1, const float* __restrict__ b2,
               const u16* __restrict__ wsw, float* __restrict__ out)
{
    __shared__ __align__(16) u16 s_A[128 * LDA];                 // 51.2 KB
    __shared__ __align__(16) u16 s_Q[128 * LDA];                 // 51.2 KB
    __shared__ __align__(16) u16 s_R3[128 * LDPU + 2*32*LDVT];   // 44.0 KB

    float* const Sf  = (float*)s_R3;            // [128][68] f32
    u16*  const PU   = s_R3;                    // [128][136] u16 (same bytes)
    u16*  const Vt   = s_R3 + 128 * LDPU;       // [2][32][72] u16
    u16*  const s_H  = s_R3;                    // [128][<=128] MLP hidden chunk
    u16*  const s_XW = s_Q;                     // xw after attention

    const int wid0 = blockIdx.x * 2;            // window A id (even)
    const int b   = wid0 >> 6;
    const int wi  = (wid0 >> 3) & 7;
    const int wjA = wid0 & 7;                   // even; window B = wjA+1 (<=7)
    const int tid  = threadIdx.x;
    const int wv   = tid >> 6;                  // 0..7
    const int lane = tid & 63;
    const int ar   = lane & 15;
    const int ak   = (lane >> 4) << 3;
    const int rg0  = (lane >> 4) << 2;
    const float scale = 0.1767766952966369f;    // 1/sqrt(32)

    const u16* Wqkvt = wsw + OFF_QKV;
    const u16* Wpt   = wsw + OFF_PW;
    const u16* W1t   = wsw + OFF_W1;
    const u16* W2t   = wsw + OFF_W2;

    // ---- P1: gather (shift -SSH) + LN1 -> s_A [128][192]; pad rows zero ----
    for (int t = wv; t < 128; t += 8) {
        const int w = t >> 6, tr = t & 63;
        if (tr < NTOK) {
            const int wjx = wjA + w;
            const int pi = tr / 7, pj = tr - pi * 7;
            const int si = (wi * WSZ + pi + SSH) % HH;
            const int sj = (wjx * WSZ + pj + SSH) % HH;
            const float* src = x + ((size_t)b * LTOT + si * HH + sj) * DIMC;
            float v0 = src[lane], v1 = src[lane + 64], v2 = src[lane + 128];
            float s  = v0 + v1 + v2;
            float s2 = v0 * v0 + v1 * v1 + v2 * v2;
#pragma unroll
            for (int off = 32; off > 0; off >>= 1) {
                s  += __shfl_xor(s,  off);
                s2 += __shfl_xor(s2, off);
            }
            const float mu   = s * (1.f / 192.f);
            const float rstd = rsqrtf(s2 * (1.f / 192.f) - mu * mu + 1e-5f);
            s_A[t*LDA + lane      ] = f2bf((v0-mu)*rstd*g1[lane]     + be1[lane]);
            s_A[t*LDA + lane + 64 ] = f2bf((v1-mu)*rstd*g1[lane+64]  + be1[lane+64]);
            s_A[t*LDA + lane + 128] = f2bf((v2-mu)*rstd*g1[lane+128] + be1[lane+128]);
        } else {
            s_A[t*LDA + lane] = 0; s_A[t*LDA + lane + 64] = 0; s_A[t*LDA + lane + 128] = 0;
        }
    }
    __syncthreads();

    // ---- attention: 3 groups x 2 heads; O in 12 named per-wave accs ----
    f32x4 o0, o1, o2, o3, o4, o5, o6, o7, o8, o9, o10, o11;
    const int g   = wv >> 2;        // window this wave serves in attention
    const int q   = wv & 3;         // sub-wave index within window
    const int rb  = g * 64;         // row base of this window

#define QKV_GROUP(G) { \
    for (int nt = wv; nt < 12; nt += 8) { \
        const int section = nt >> 2, idxq = nt & 3; \
        const int gcol = section*192 + (G)*64 + idxq*16 + ar; \
        const int lcol = section*64 + idxq*16 + ar; \
        const float bias = qkv_b[gcol]; \
        const u16* wc = Wqkvt + (size_t)gcol * 384; \
        f32x4 acc[8]; \
        _Pragma("unroll") for (int mt = 0; mt < 8; mt++) acc[mt] = 0; \
        _Pragma("unroll") \
        for (int kk = 0; kk < 6; kk++) { \
            bf16x8 bh = *(const bf16x8*)&wc[kk*32 + ak]; \
            bf16x8 bl = *(const bf16x8*)&wc[192 + kk*32 + ak]; \
            _Pragma("unroll") \
            for (int mt = 0; mt < 8; mt++) { \
                bf16x8 a = *(const bf16x8*)&s_A[(mt*16 + ar)*LDA + kk*32 + ak]; \
                acc[mt] = MFMA(a, bh, acc[mt]); \
                acc[mt] = MFMA(a, bl, acc[mt]); \
            } \
        } \
        _Pragma("unroll") \
        for (int mt = 0; mt < 8; mt++) \
            _Pragma("unroll") \
            for (int rg = 0; rg < 4; rg++) \
                s_Q[(mt*16 + rg0 + rg)*LDA + lcol] = f2bf(acc[mt][rg] + bias); \
    } } __syncthreads();

#define ATTN_HEAD(HL, O0, O1) { \
    { /* S = scale * Q K^T per window; wave q owns col-tile q */ \
        bf16x8 bk = *(const bf16x8*)&s_Q[(rb + q*16 + ar)*LDA + 64 + (HL)*32 + ak]; \
        _Pragma("unroll") \
        for (int mt = 0; mt < 4; mt++) { \
            bf16x8 aq = *(const bf16x8*)&s_Q[(rb + mt*16 + ar)*LDA + (HL)*32 + ak]; \
            f32x4 sa; sa = 0; \
            sa = MFMA(aq, bk, sa); \
            _Pragma("unroll") \
            for (int rg = 0; rg < 4; rg++) \
                Sf[(rb + mt*16 + rg0 + rg)*LDSS + q*16 + ar] = sa[rg] * scale; \
        } } \
    __syncthreads(); \
    { /* softmax 128 rows (4 lanes/row, in-regs) -> P hi|lo; Vt fill */ \
        const int row = tid >> 2, sub = tid & 3, lr = row & 63; \
        if (lr < NTOK) { \
            float e[16]; float m = -1e30f; \
            _Pragma("unroll") \
            for (int i = 0; i < 16; i++) { \
                const int j = sub + 4*i; \
                e[i] = (j < NTOK) ? Sf[row*LDSS + j] : -1e30f; \
                m = fmaxf(m, e[i]); \
            } \
            m = fmaxf(m, __shfl_xor(m, 1)); \
            m = fmaxf(m, __shfl_xor(m, 2)); \
            float sum = 0.f; \
            _Pragma("unroll") \
            for (int i = 0; i < 16; i++) { e[i] = __expf(e[i] - m); sum += e[i]; } \
            sum += __shfl_xor(sum, 1); \
            sum += __shfl_xor(sum, 2); \
            const float inv = 1.f / sum; \
            _Pragma("unroll") \
            for (int i = 0; i < 16; i++) { \
                const int j = sub + 4*i; \
                const float p = e[i] * inv; \
                const u16 hb = f2bf(p); \
                PU[row*LDPU + j] = hb; \
                PU[row*LDPU + 64 + j] = f2bf(p - bf2f(hb)); \
            } \
        } \
        for (int i2 = tid; i2 < 4096; i2 += 512) { \
            const int w = i2 >> 11, rem = i2 & 2047; \
            const int d = rem & 31, j = rem >> 5; \
            Vt[w*2304 + d*LDVT + j] = \
                (j < NTOK) ? s_Q[(w*64 + j)*LDA + 128 + (HL)*32 + d] : (u16)0; \
        } } \
    __syncthreads(); \
    { /* O = (Phi+Plo) @ V : per window 8 tiles over 4 waves */ \
        const int dcol = (q & 1)*16 + ar; \
        const int mtb = (q >> 1) << 1; \
        f32x4 accv; \
        accv = 0; \
        _Pragma("unroll") \
        for (int kk = 0; kk < 2; kk++) { \
            bf16x8 ph = *(const bf16x8*)&PU[(rb + (mtb+0)*16 + ar)*LDPU + kk*32 + ak]; \
            bf16x8 pl = *(const bf16x8*)&PU[(rb + (mtb+0)*16 + ar)*LDPU + 64 + kk*32 + ak]; \
            bf16x8 bv = *(const bf16x8*)&Vt[g*2304 + dcol*LDVT + kk*32 + ak]; \
            accv = MFMA(ph, bv, accv); \
            accv = MFMA(pl, bv, accv); \
        } \
        O0 = accv; \
        accv = 0; \
        _Pragma("unroll") \
        for (int kk = 0; kk < 2; kk++) { \
            bf16x8 ph = *(const bf16x8*)&PU[(rb + (mtb+1)*16 + ar)*LDPU + kk*32 + ak]; \
            bf16x8 pl = *(const bf16x8*)&PU[(rb + (mtb+1)*16 + ar)*LDPU + 64 + kk*32 + ak]; \
            bf16x8 bv = *(const bf16x8*)&Vt[g*2304 + dcol*LDVT + kk*32 + ak]; \
            accv = MFMA(ph, bv, accv); \
            accv = MFMA(pl, bv, accv); \
        } \
        O1 = accv; } \
    __syncthreads(); }

#define OSTORE(HEADIDX, OV0, OV1) { \
    const int col = (HEADIDX)*32 + (q & 1)*16 + ar; \
    const int mtb = (q >> 1) << 1; \
    _Pragma("unroll") \
    for (int rg = 0; rg < 4; rg++) { \
        s_A[(rb + (mtb+0)*16 + rg0 + rg)*LDA + col] = f2bf(OV0[rg]); \
        s_A[(rb + (mtb+1)*16 + rg0 + rg)*LDA + col] = f2bf(OV1[rg]); \
    } }

    QKV_GROUP(0)
    ATTN_HEAD(0, o0, o1)
    ATTN_HEAD(1, o2, o3)
    QKV_GROUP(1)
    ATTN_HEAD(0, o4, o5)
    ATTN_HEAD(1, o6, o7)
    QKV_GROUP(2)
    ATTN_HEAD(0, o8, o9)
    ATTN_HEAD(1, o10, o11)

    // xn fully consumed; O -> s_A (pad rows get zeros: P pad rows are 0)
    OSTORE(0, o0, o1)  OSTORE(1, o2, o3)  OSTORE(2, o4, o5)
    OSTORE(3, o6, o7)  OSTORE(4, o8, o9)  OSTORE(5, o10, o11)
    __syncthreads();

    // ---- P4: xw = O @ (Wp hi+lo) + b, M=128 -> s_XW ----
    for (int nt = wv; nt < 12; nt += 8) {
        const int col = nt*16 + ar;
        const float bias = proj_b[col];
        const u16* wc = Wpt + (size_t)col * 384;
        f32x4 acc[8];
#pragma unroll
        for (int mt = 0; mt < 8; mt++) acc[mt] = 0;
#pragma unroll
        for (int kk = 0; kk < 6; kk++) {
            bf16x8 bh = *(const bf16x8*)&wc[kk*32 + ak];
            bf16x8 bl = *(const bf16x8*)&wc[192 + kk*32 + ak];
#pragma unroll
            for (int mt = 0; mt < 8; mt++) {
                bf16x8 a = *(const bf16x8*)&s_A[(mt*16 + ar)*LDA + kk*32 + ak];
                acc[mt] = MFMA(a, bh, acc[mt]);
                acc[mt] = MFMA(a, bl, acc[mt]);
            }
        }
#pragma unroll
        for (int mt = 0; mt < 8; mt++)
#pragma unroll
            for (int rg = 0; rg < 4; rg++)
                s_XW[(mt*16 + rg0 + rg)*LDA + col] = f2bf(acc[mt][rg] + bias);
    }
    __syncthreads();

    // ---- P5: LN2(xw) -> s_A (valid rows only; pad rows stay 0) ----
    for (int t = wv; t < 128; t += 8) {
        const int tr = t & 63;
        if (tr < NTOK) {
            float v0 = bf2f(s_XW[t*LDA + lane      ]);
            float v1 = bf2f(s_XW[t*LDA + lane + 64 ]);
            float v2 = bf2f(s_XW[t*LDA + lane + 128]);
            float s  = v0 + v1 + v2;
            float s2 = v0*v0 + v1*v1 + v2*v2;
#pragma unroll
            for (int off = 32; off > 0; off >>= 1) {
                s  += __shfl_xor(s,  off);
                s2 += __shfl_xor(s2, off);
            }
            const float mu   = s * (1.f / 192.f);
            const float rstd = rsqrtf(s2 * (1.f / 192.f) - mu * mu + 1e-5f);
            s_A[t*LDA + lane      ] = f2bf((v0-mu)*rstd*g2[lane]     + be2[lane]);
            s_A[t*LDA + lane + 64 ] = f2bf((v1-mu)*rstd*g2[lane+64]  + be2[lane+64]);
            s_A[t*LDA + lane + 128] = f2bf((v2-mu)*rstd*g2[lane+128] + be2[lane+128]);
        }
    }
    __syncthreads();

    // ---- P6: MLP, hidden in 6 chunks of 128; GEMM2 accum in regs ----
    f32x4 accO[2][8];
#pragma unroll
    for (int t = 0; t < 2; t++)
#pragma unroll
        for (int m = 0; m < 8; m++) accO[t][m] = 0;

    for (int cc = 0; cc < 6; cc++) {
        {   // MLP1: one 16-col tile per wave (128 cols per chunk)
            const int ncol = wv*16 + ar;
            const int ngl  = cc*128 + ncol;
            const float bias = b1[ngl];
            const u16* wc = W1t + (size_t)ngl * 384;
            f32x4 acc[8];
#pragma unroll
            for (int mt = 0; mt < 8; mt++) acc[mt] = 0;
#pragma unroll
            for (int kk = 0; kk < 6; kk++) {
                bf16x8 bh = *(const bf16x8*)&wc[kk*32 + ak];
                bf16x8 bl = *(const bf16x8*)&wc[192 + kk*32 + ak];
#pragma unroll
                for (int mt = 0; mt < 8; mt++) {
                    bf16x8 a = *(const bf16x8*)&s_A[(mt*16 + ar)*LDA + kk*32 + ak];
                    acc[mt] = MFMA(a, bh, acc[mt]);
                    acc[mt] = MFMA(a, bl, acc[mt]);
                }
            }
#pragma unroll
            for (int mt = 0; mt < 8; mt++)
#pragma unroll
                for (int rg = 0; rg < 4; rg++) {
                    const float z = acc[mt][rg] + bias;
                    const float ge = 0.5f * z * (1.f + erff(z * 0.70710678118654752f));
                    s_H[(mt*16 + rg0 + rg)*LDH + ncol] = f2bf(ge);
                }
        }
        __syncthreads();
        {   // MLP2 partial over this 128-wide K chunk
#pragma unroll
            for (int tt = 0; tt < 2; tt++) {
                const int nt = wv + tt*8;
                if (nt < 12) {
                    const int col = nt*16 + ar;
                    const u16* wc = W2t + (size_t)col * 1536 + cc*128;
#pragma unroll
                    for (int kk = 0; kk < 4; kk++) {
                        bf16x8 bh = *(const bf16x8*)&wc[kk*32 + ak];
                        bf16x8 bl = *(const bf16x8*)&wc[768 + kk*32 + ak];
#pragma unroll
                        for (int mt = 0; mt < 8; mt++) {
                            bf16x8 ah = *(const bf16x8*)&s_H[(mt*16 + ar)*LDH + kk*32 + ak];
                            accO[tt][mt] = MFMA(ah, bh, accO[tt][mt]);
                            accO[tt][mt] = MFMA(ah, bl, accO[tt][mt]);
                        }
                    }
                }
            }
        }
        __syncthreads();
    }

    // ---- P7: out = accO + b2 + residual(xw), reverse-shift scatter ----
#pragma unroll
    for (int tt = 0; tt < 2; tt++) {
        const int nt = wv + tt*8;
        if (nt < 12) {
            const int col = nt*16 + ar;
            const float bias = b2[col];
#pragma unroll
            for (int mt = 0; mt < 8; mt++)
#pragma unroll
                for (int rg = 0; rg < 4; rg++) {
                    const int row = mt*16 + rg0 + rg;     // 0..127
                    const int w = row >> 6, lr = row & 63;
                    if (lr < NTOK) {
                        const int wjx = wjA + w;
                        const int pi = lr / 7, pj = lr - pi * 7;
                        const int di = (wi * WSZ + pi + SSH) % HH;
                        const int dj = (wjx * WSZ + pj + SSH) % HH;
                        out[((size_t)b * LTOT + di * HH + dj) * DIMC + col] =
                            accO[tt][mt][rg] + bias + bf2f(s_XW[row*LDA + col]);
                    }
                }
        }
    }
#undef QKV_GROUP
#undef ATTN_HEAD
#undef OSTORE
}

// ---------------------------------------------------------------------------
// Fallback: round-2 scalar kernel (known-good), used only if ws too small.
// ---------------------------------------------------------------------------
__global__ __launch_bounds__(256, 1)
void swin_fallback(const float* __restrict__ x,
                   const float* __restrict__ qkv_w, const float* __restrict__ qkv_b,
                   const float* __restrict__ proj_w, const float* __restrict__ proj_b,
                   const float* __restrict__ g1, const float* __restrict__ be1,
                   const float* __restrict__ g2, const float* __restrict__ be2,
                   const float* __restrict__ w1, const float* __restrict__ b1,
                   const float* __restrict__ w2, const float* __restrict__ b2,
                   float* __restrict__ out)
{
    __shared__ __align__(16) u16  s_A[NTOK * DIMC];
    __shared__ __align__(16) u16  s_B[NTOK * 3 * DIMC];
    __shared__ __align__(16) float s_S[NTOK * 52];

    const int wid = blockIdx.x;
    const int b  = wid >> 6;
    const int wi = (wid >> 3) & 7;
    const int wj = wid & 7;
    const int tid  = threadIdx.x;
    const int wave = tid >> 6;
    const int lane = tid & 63;

    for (int t = wave; t < NTOK; t += 4) {
        const int pi = t / 7, pj = t - pi * 7;
        const int si = (wi * WSZ + pi + SSH) % HH;
        const int sj = (wj * WSZ + pj + SSH) % HH;
        const size_t base = ((size_t)b * LTOT + si * HH + sj) * DIMC;
        float v0 = x[base + lane], v1 = x[base + lane + 64], v2 = x[base + lane + 128];
        float s = v0+v1+v2, s2 = v0*v0+v1*v1+v2*v2;
#pragma unroll
        for (int off = 32; off > 0; off >>= 1) { s += __shfl_xor(s, off); s2 += __shfl_xor(s2, off); }
        const float mu = s * (1.f/192.f);
        const float rstd = rsqrtf(s2 * (1.f/192.f) - mu*mu + 1e-5f);
        s_A[t*DIMC + lane      ] = f2bf((v0-mu)*rstd*g1[lane]     + be1[lane]);
        s_A[t*DIMC + lane + 64 ] = f2bf((v1-mu)*rstd*g1[lane+64]  + be1[lane+64]);
        s_A[t*DIMC + lane + 128] = f2bf((v2-mu)*rstd*g1[lane+128] + be1[lane+128]);
    }
    __syncthreads();
    {
        const u32* xn2 = reinterpret_cast<const u32*>(s_A);
        for (int n = tid; n < 3*DIMC; n += 256) {
            const float bias = qkv_b[n];
            for (int t0 = 0; t0 < NTOK; t0 += 16) {
                const int tn = (NTOK - t0) < 16 ? (NTOK - t0) : 16;
                float acc[16];
#pragma unroll
                for (int i = 0; i < 16; i++) acc[i] = 0.f;
                for (int k = 0; k < DIMC; k += 2) {
                    const float wv0 = qkv_w[(size_t)k*(3*DIMC) + n];
                    const float wv1 = qkv_w[(size_t)(k+1)*(3*DIMC) + n];
#pragma unroll
                    for (int i = 0; i < 16; i++)
                        if (i < tn) {
                            u32 u = xn2[((t0+i)*DIMC + k) >> 1];
                            acc[i] += bf2f((u16)u)*wv0 + bf2f((u16)(u>>16))*wv1;
                        }
                }
                for (int i = 0; i < tn; i++) s_B[(t0+i)*(3*DIMC) + n] = f2bf(acc[i] + bias);
            }
        }
    }
    __syncthreads();
    const float scale = 0.1767766952966369f;
    for (int h = 0; h < 6; h++) {
        for (int idx = tid; idx < NTOK*NTOK; idx += 256) {
            const int i = idx / NTOK, j = idx - i*NTOK;
            const u32* qp = reinterpret_cast<const u32*>(&s_B[i*(3*DIMC) + h*32]);
            const u32* kp = reinterpret_cast<const u32*>(&s_B[j*(3*DIMC) + DIMC + h*32]);
            float acc = 0.f;
#pragma unroll
            for (int d = 0; d < 16; d++) {
                const u32 qu = qp[d], ku = kp[d];
                acc += bf2f((u16)qu)*bf2f((u16)ku) + bf2f((u16)(qu>>16))*bf2f((u16)(ku>>16));
            }
            s_S[i*52 + j] = acc * scale;
        }
        __syncthreads();
        if (tid < NTOK) {
            float m = -1e30f;
            for (int j = 0; j < NTOK; j++) m = fmaxf(m, s_S[tid*52 + j]);
            float sum = 0.f;
            for (int j = 0; j < NTOK; j++) { float e = __expf(s_S[tid*52+j]-m); s_S[tid*52+j] = e; sum += e; }
            const float inv = 1.f/sum;
            for (int j = 0; j < NTOK; j++) s_S[tid*52+j] *= inv;
        }
        __syncthreads();
        for (int idx = tid; idx < NTOK*32; idx += 256) {
            const int i = idx >> 5, d = idx & 31;
            float acc = 0.f;
            for (int j = 0; j < NTOK; j++)
                acc += s_S[i*52+j] * bf2f(s_B[j*(3*DIMC) + 2*DIMC + h*32 + d]);
            s_A[i*DIMC + h*32 + d] = f2bf(acc);
        }
        __syncthreads();
    }
    if (tid < DIMC) {
        const int n = tid;
        const float bias = proj_b[n];
        const u32* O2 = reinterpret_cast<const u32*>(s_A);
        for (int t0 = 0; t0 < NTOK; t0 += 16) {
            const int tn = (NTOK - t0) < 16 ? (NTOK - t0) : 16;
            float acc[16];
#pragma unroll
            for (int i = 0; i < 16; i++) acc[i] = 0.f;
            for (int k = 0; k < DIMC; k += 2) {
                const float wv0 = proj_w[k*DIMC + n];
                const float wv1 = proj_w[(k+1)*DIMC + n];
#pragma unroll
                for (int i = 0; i < 16; i++)
                    if (i < tn) {
                        u32 u = O2[((t0+i)*DIMC + k) >> 1];
                        acc[i] += bf2f((u16)u)*wv0 + bf2f((u16)(u>>16))*wv1;
                    }
            }
            for (int i = 0; i < tn; i++) s_B[(t0+i)*DIMC + n] = f2bf(acc[i] + bias);
        }
    }
    __syncthreads();
    for (int t = wave; t < NTOK; t += 4) {
        float v0 = bf2f(s_B[t*DIMC + lane]);
        float v1 = bf2f(s_B[t*DIMC + lane + 64]);
        float v2 = bf2f(s_B[t*DIMC + lane + 128]);
        float s = v0+v1+v2, s2 = v0*v0+v1*v1+v2*v2;
#pragma unroll
        for (int off = 32; off > 0; off >>= 1) { s += __shfl_xor(s, off); s2 += __shfl_xor(s2, off); }
        const float mu = s * (1.f/192.f);
        const float rstd = rsqrtf(s2 * (1.f/192.f) - mu*mu + 1e-5f);
        s_A[t*DIMC + lane      ] = f2bf((v0-mu)*rstd*g2[lane]     + be2[lane]);
        s_A[t*DIMC + lane + 64 ] = f2bf((v1-mu)*rstd*g2[lane+64]  + be2[lane+64]);
        s_A[t*DIMC + lane + 128] = f2bf((v2-mu)*rstd*g2[lane+128] + be2[lane+128]);
    }
    __syncthreads();
    u16* s_h = s_B + NTOK * DIMC;
    for (int tg = 0; tg < 4; tg++) {
        const int tbase = tg * 13;
        const int tcnt = (NTOK - tbase) < 13 ? (NTOK - tbase) : 13;
        {
            const u32* xl2 = reinterpret_cast<const u32*>(s_A);
            for (int n = tid; n < HIDDEN; n += 256) {
                float acc[13];
#pragma unroll
                for (int i = 0; i < 13; i++) acc[i] = 0.f;
                for (int k = 0; k < DIMC; k += 2) {
                    const float wv0 = w1[(size_t)k*HIDDEN + n];
                    const float wv1 = w1[(size_t)(k+1)*HIDDEN + n];
#pragma unroll
                    for (int i = 0; i < 13; i++)
                        if (i < tcnt) {
                            u32 u = xl2[((tbase+i)*DIMC + k) >> 1];
                            acc[i] += bf2f((u16)u)*wv0 + bf2f((u16)(u>>16))*wv1;
                        }
                }
                const float bb = b1[n];
                for (int i = 0; i < tcnt; i++) {
                    const float z = acc[i] + bb;
                    s_h[i*HIDDEN + n] = f2bf(0.5f*z*(1.f + erff(z*0.70710678118f)));
                }
            }
        }
        __syncthreads();
        if (tid < DIMC) {
            const int n = tid;
            const u32* h2 = reinterpret_cast<const u32*>(s_h);
            float acc[13];
#pragma unroll
            for (int i = 0; i < 13; i++) acc[i] = 0.f;
            for (int k = 0; k < HIDDEN; k += 2) {
                const float wv0 = w2[(size_t)k*DIMC + n];
                const float wv1 = w2[(size_t)(k+1)*DIMC + n];
#pragma unroll
                for (int i = 0; i < 13; i++)
                    if (i < tcnt) {
                        u32 u = h2[(i*HIDDEN + k) >> 1];
                        acc[i] += bf2f((u16)u)*wv0 + bf2f((u16)(u>>16))*wv1;
                    }
            }
            const float bb = b2[n];
            for (int i = 0; i < tcnt; i++) {
                const int t = tbase + i;
                const int pi = t / 7, pj = t - pi*7;
                const int di = (wi*WSZ + pi + SSH) % HH;
                const int dj = (wj*WSZ + pj + SSH) % HH;
                out[((size_t)b*LTOT + di*HH + dj)*DIMC + n] = acc[i] + bb + bf2f(s_B[t*DIMC + n]);
            }
        }
        __syncthreads();
    }
}

extern "C" void kernel_launch(void* const* d_in, const int* in_sizes, int n_in,
                              void* d_out, int out_size, void* d_ws, size_t ws_size,
                              hipStream_t stream)
{
    const float* x      = (const float*)d_in[0];
    const float* qkv_w  = (const float*)d_in[1];
    const float* qkv_b  = (const float*)d_in[2];
    const float* proj_w = (const float*)d_in[3];
    const float* proj_b = (const float*)d_in[4];
    const float* g1     = (const float*)d_in[5];
    const float* be1    = (const float*)d_in[6];
    const float* g2     = (const float*)d_in[7];
    const float* be2    = (const float*)d_in[8];
    const float* w1     = (const float*)d_in[9];
    const float* b1     = (const float*)d_in[10];
    const float* w2     = (const float*)d_in[11];
    const float* b2     = (const float*)d_in[12];
    float* out = (float*)d_out;

    if (ws_size >= (size_t)WS_BYTES) {
        cvt_weights<<<256, 256, 0, stream>>>(qkv_w, proj_w, w1, w2, (u16*)d_ws);
        swin_mfma<<<NWIN_T/2, 512, 0, stream>>>(x, qkv_b, proj_b, g1, be1, g2, be2,
                                                b1, b2, (const u16*)d_ws, out);
    } else {
        swin_fallback<<<NWIN_T, 256, 0, stream>>>(x, qkv_w, qkv_b, proj_w, proj_b,
                                                  g1, be1, g2, be2, w1, b1, w2, b2, out);
    }
}

// Round 8
// 474.304 us; speedup vs baseline: 28.8500x; 1.0280x over previous
//
#include <hip/hip_runtime.h>

typedef unsigned short u16;
typedef unsigned int   u32;
typedef __attribute__((ext_vector_type(8))) short bf16x8;
typedef __attribute__((ext_vector_type(4))) float f32x4;

#define DIMC   192
#define HH     56
#define WSZ    7
#define SSH    3
#define NTOK   49
#define NWIN_T 2048
#define HIDDEN 768
#define LTOT   3136

#define LDA    200    // u16 row stride, [64][<=192] tiles (400B rows)
#define LDSS   68     // f32 row stride of S
#define LDPU   136    // u16 view (2*LDSS): hi cols 0-63, lo cols 64-127
#define LDVT   72     // u16 row stride of V^T
#define LDH2   72     // u16 row stride of K2 h-chunk (144B rows, 16B-aligned)

// ws layout (u16 elems): per weight col, [K hi | K lo] contiguous (stride 2K)
#define OFF_QKV 0                         // 576 cols * 384
#define OFF_PW  221184                    // + 192 * 384
#define OFF_W1  294912                    // + 768 * 384
#define OFF_W2  589824                    // + 192 * 1536
#define WS_ELEMS 884736
#define WS_BYTES (WS_ELEMS * 2)
#define XATTN_BYTES ((size_t)NWIN_T * NTOK * DIMC * 2)   // 38.5 MB bf16

#define MFMA(a,b,c) __builtin_amdgcn_mfma_f32_16x16x32_bf16((a),(b),(c),0,0,0)

__device__ __forceinline__ float bf2f(u16 u) {
    union { u32 i; float f; } v; v.i = ((u32)u) << 16; return v.f;
}
__device__ __forceinline__ u16 f2bf(float f) {
    union { float ff; u32 i; } v; v.ff = f;
    u32 x = v.i;
    return (u16)((x + 0x7FFFu + ((x >> 16) & 1u)) >> 16);  // RNE
}
__device__ __forceinline__ void split_store(u16* hi, u16* lo, float w) {
    u16 h = f2bf(w);
    *hi = h;
    *lo = f2bf(w - bf2f(h));
}

// ---------------------------------------------------------------------------
// Prep: fp32 [K][N] -> split bf16 W^T stored [N][ hi[0:K] | lo[0:K] ].
// ---------------------------------------------------------------------------
__global__ void cvt_weights(const float* __restrict__ qkv_w,
                            const float* __restrict__ proj_w,
                            const float* __restrict__ w1,
                            const float* __restrict__ w2,
                            u16* __restrict__ ws)
{
    const int idx = blockIdx.x * blockDim.x + threadIdx.x;
    const int stride = gridDim.x * blockDim.x;
    for (int i = idx; i < 110592; i += stride) {        // qkv [192][576]
        int k = i / 576, n = i - k * 576;
        u16* base = ws + OFF_QKV + (size_t)n * 384;
        split_store(base + k, base + 192 + k, qkv_w[i]);
    }
    for (int i = idx; i < 36864; i += stride) {         // proj [192][192]
        int k = i / 192, n = i - k * 192;
        u16* base = ws + OFF_PW + (size_t)n * 384;
        split_store(base + k, base + 192 + k, proj_w[i]);
    }
    for (int i = idx; i < 147456; i += stride) {        // w1 [192][768]
        int k = i / 768, n = i - k * 768;
        u16* base = ws + OFF_W1 + (size_t)n * 384;
        split_store(base + k, base + 192 + k, w1[i]);
    }
    for (int i = idx; i < 147456; i += stride) {        // w2 [768][192]
        int k = i / 192, n = i - k * 192;
        u16* base = ws + OFF_W2 + (size_t)n * 1536;
        split_store(base + k, base + 768 + k, w2[i]);
    }
}

// ---------------------------------------------------------------------------
// P1: gather (shift -SSH) + LN1 -> s_A [64][192]; pad rows 49..63 zeroed.
// ---------------------------------------------------------------------------
__device__ __forceinline__ void ln1_gather(
    const float* __restrict__ x, const float* __restrict__ g1,
    const float* __restrict__ be1, u16* __restrict__ s_A,
    int b, int wi, int wj, int wv, int lane)
{
    for (int t = wv; t < 64; t += 4) {
        if (t < NTOK) {
            const int pi = t / 7, pj = t - pi * 7;
            const int si = (wi * WSZ + pi + SSH) % HH;
            const int sj = (wj * WSZ + pj + SSH) % HH;
            const float* src = x + ((size_t)b * LTOT + si * HH + sj) * DIMC;
            float v0 = src[lane], v1 = src[lane + 64], v2 = src[lane + 128];
            float s  = v0 + v1 + v2;
            float s2 = v0 * v0 + v1 * v1 + v2 * v2;
#pragma unroll
            for (int off = 32; off > 0; off >>= 1) {
                s  += __shfl_xor(s,  off);
                s2 += __shfl_xor(s2, off);
            }
            const float mu   = s * (1.f / 192.f);
            const float rstd = rsqrtf(s2 * (1.f / 192.f) - mu * mu + 1e-5f);
            s_A[t*LDA + lane      ] = f2bf((v0-mu)*rstd*g1[lane]     + be1[lane]);
            s_A[t*LDA + lane + 64 ] = f2bf((v1-mu)*rstd*g1[lane+64]  + be1[lane+64]);
            s_A[t*LDA + lane + 128] = f2bf((v2-mu)*rstd*g1[lane+128] + be1[lane+128]);
        } else {
            s_A[t*LDA + lane] = 0; s_A[t*LDA + lane + 64] = 0; s_A[t*LDA + lane + 128] = 0;
        }
    }
}

// ---------------------------------------------------------------------------
// attention: 3 QKV groups x 2 heads; MFMA QK^T, wave-parallel fp32 softmax,
// split hi/lo P MFMA PV. Starts with xn in s_A; ends with O in s_A (+barrier).
// ---------------------------------------------------------------------------
__device__ __forceinline__ void attn_all(
    u16* __restrict__ s_A, u16* __restrict__ s_Q,
    float* __restrict__ Sf, u16* __restrict__ PU, u16* __restrict__ Vt,
    const u16* __restrict__ Wqkvt, const float* __restrict__ qkv_b,
    int tid, int wv, int ar, int ak, int rg0)
{
    const float scale = 0.1767766952966369f;   // 1/sqrt(32)
    f32x4 o[12];

#pragma unroll
    for (int G = 0; G < 3; G++) {
        // ---- QKV group G -> s_Q cols [0:64)=Q [64:128)=K [128:192)=V ----
#pragma unroll
        for (int tl = 0; tl < 3; tl++) {
            const int tt = wv*3 + tl;
            const int section = tt >> 2, idxq = tt & 3;
            const int gcol = section*192 + G*64 + idxq*16 + ar;
            const int lcol = section*64 + idxq*16 + ar;
            const float bias = qkv_b[gcol];
            const u16* wc = Wqkvt + (size_t)gcol * 384;
            f32x4 acc[4];
#pragma unroll
            for (int mt = 0; mt < 4; mt++) acc[mt] = 0;
#pragma unroll
            for (int kk = 0; kk < 6; kk++) {
                bf16x8 bh = *(const bf16x8*)&wc[kk*32 + ak];
                bf16x8 bl = *(const bf16x8*)&wc[192 + kk*32 + ak];
#pragma unroll
                for (int mt = 0; mt < 4; mt++) {
                    bf16x8 a = *(const bf16x8*)&s_A[(mt*16 + ar)*LDA + kk*32 + ak];
                    acc[mt] = MFMA(a, bh, acc[mt]);
                    acc[mt] = MFMA(a, bl, acc[mt]);
                }
            }
#pragma unroll
            for (int mt = 0; mt < 4; mt++)
#pragma unroll
                for (int rg = 0; rg < 4; rg++)
                    s_Q[(mt*16 + rg0 + rg)*LDA + lcol] = f2bf(acc[mt][rg] + bias);
        }
        __syncthreads();

#pragma unroll
        for (int HL = 0; HL < 2; HL++) {
            // ---- S = scale * Q K^T ; wave wv owns col-tile wv ----
            {
                bf16x8 bk = *(const bf16x8*)&s_Q[(wv*16 + ar)*LDA + 64 + HL*32 + ak];
#pragma unroll
                for (int mt = 0; mt < 4; mt++) {
                    bf16x8 aq = *(const bf16x8*)&s_Q[(mt*16 + ar)*LDA + HL*32 + ak];
                    f32x4 sa; sa = 0;
                    sa = MFMA(aq, bk, sa);
#pragma unroll
                    for (int rg = 0; rg < 4; rg++)
                        Sf[(mt*16 + rg0 + rg)*LDSS + wv*16 + ar] = sa[rg] * scale;
                }
            }
            __syncthreads();
            // ---- softmax (4 lanes/row, regs) -> P hi|lo; Vt fill ----
            {
                const int row = tid >> 2, sub = tid & 3;
                if (row < NTOK) {
                    float e[16]; float m = -1e30f;
#pragma unroll
                    for (int i = 0; i < 16; i++) {
                        const int j = sub + 4*i;
                        e[i] = (j < NTOK) ? Sf[row*LDSS + j] : -1e30f;
                        m = fmaxf(m, e[i]);
                    }
                    m = fmaxf(m, __shfl_xor(m, 1));
                    m = fmaxf(m, __shfl_xor(m, 2));
                    float sum = 0.f;
#pragma unroll
                    for (int i = 0; i < 16; i++) { e[i] = __expf(e[i] - m); sum += e[i]; }
                    sum += __shfl_xor(sum, 1);
                    sum += __shfl_xor(sum, 2);
                    const float inv = 1.f / sum;
#pragma unroll
                    for (int i = 0; i < 16; i++) {
                        const int j = sub + 4*i;
                        const float p = e[i] * inv;   // 0 for j>=49 -> pad cols zero
                        const u16 hb = f2bf(p);
                        PU[row*LDPU + j] = hb;
                        PU[row*LDPU + 64 + j] = f2bf(p - bf2f(hb));
                    }
                }
                for (int i2 = tid; i2 < 2048; i2 += 256) {
                    const int d = i2 & 31, j = i2 >> 5;
                    Vt[d*LDVT + j] = (j < NTOK) ? s_Q[j*LDA + 128 + HL*32 + d] : (u16)0;
                }
            }
            __syncthreads();
            // ---- O = (Phi+Plo) @ V : 8 tiles over 4 waves, 2 per wave ----
            {
                const int dcol = (wv & 1)*16 + ar;
                const int mtb = (wv >> 1) << 1;
#pragma unroll
                for (int mi = 0; mi < 2; mi++) {
                    f32x4 accv; accv = 0;
#pragma unroll
                    for (int kk = 0; kk < 2; kk++) {
                        bf16x8 ph = *(const bf16x8*)&PU[((mtb+mi)*16 + ar)*LDPU + kk*32 + ak];
                        bf16x8 pl = *(const bf16x8*)&PU[((mtb+mi)*16 + ar)*LDPU + 64 + kk*32 + ak];
                        bf16x8 bv = *(const bf16x8*)&Vt[dcol*LDVT + kk*32 + ak];
                        accv = MFMA(ph, bv, accv);
                        accv = MFMA(pl, bv, accv);
                    }
                    o[(G*2 + HL)*2 + mi] = accv;
                }
            }
            __syncthreads();
        }
    }

    // ---- O -> s_A (xn dead; pad rows receive zeros since P pad rows = 0) ----
    {
        const int mtb = (wv >> 1) << 1;
        const int cbase = (wv & 1)*16 + ar;
#pragma unroll
        for (int hp = 0; hp < 6; hp++) {
            const int col = hp*32 + cbase;
#pragma unroll
            for (int mi = 0; mi < 2; mi++)
#pragma unroll
                for (int rg = 0; rg < 4; rg++)
                    s_A[((mtb+mi)*16 + rg0 + rg)*LDA + col] = f2bf(o[hp*2 + mi][rg]);
        }
    }
    __syncthreads();
}

// ---------------------------------------------------------------------------
// K1: LN1 + QKV + attention + proj -> xattn (bf16, window-major [2048][49][192])
// ---------------------------------------------------------------------------
__global__ __launch_bounds__(256, 2)
void swin_attn(const float* __restrict__ x,
               const float* __restrict__ qkv_b, const float* __restrict__ proj_b,
               const float* __restrict__ g1, const float* __restrict__ be1,
               const u16* __restrict__ wsw, u16* __restrict__ xattn)
{
    __shared__ __align__(16) u16 s_A[64 * LDA];                 // 25.6 KB
    __shared__ __align__(16) u16 s_Q[64 * LDA];                 // 25.6 KB
    __shared__ __align__(16) u16 s_R3[64 * LDPU + 32 * LDVT];   // 22.0 KB

    float* const Sf = (float*)s_R3;
    u16*  const PU  = s_R3;
    u16*  const Vt  = s_R3 + 64 * LDPU;

    const int wid = blockIdx.x;
    const int b  = wid >> 6;
    const int wi = (wid >> 3) & 7;
    const int wj = wid & 7;
    const int tid  = threadIdx.x;
    const int wv   = tid >> 6;
    const int lane = tid & 63;
    const int ar   = lane & 15;
    const int ak   = (lane >> 4) << 3;
    const int rg0  = (lane >> 4) << 2;

    ln1_gather(x, g1, be1, s_A, b, wi, wj, wv, lane);
    __syncthreads();

    attn_all(s_A, s_Q, Sf, PU, Vt, wsw + OFF_QKV, qkv_b, tid, wv, ar, ak, rg0);

    // ---- proj: XW = O @ (Wp hi+lo) + b -> global xattn (bf16) ----
    {
        const u16* Wpt = wsw + OFF_PW;
        bf16x8 ao[4][6];
#pragma unroll
        for (int mt = 0; mt < 4; mt++)
#pragma unroll
            for (int kk = 0; kk < 6; kk++)
                ao[mt][kk] = *(const bf16x8*)&s_A[(mt*16 + ar)*LDA + kk*32 + ak];
#pragma unroll
        for (int ntl = 0; ntl < 3; ntl++) {
            const int col = (wv*3 + ntl)*16 + ar;
            const float bias = proj_b[col];
            const u16* wc = Wpt + (size_t)col * 384;
            bf16x8 bh[6], bl[6];
#pragma unroll
            for (int kk = 0; kk < 6; kk++) {
                bh[kk] = *(const bf16x8*)&wc[kk*32 + ak];
                bl[kk] = *(const bf16x8*)&wc[192 + kk*32 + ak];
            }
            f32x4 acc[4];
#pragma unroll
            for (int mt = 0; mt < 4; mt++) acc[mt] = 0;
#pragma unroll
            for (int kk = 0; kk < 6; kk++)
#pragma unroll
                for (int mt = 0; mt < 4; mt++) {
                    acc[mt] = MFMA(ao[mt][kk], bh[kk], acc[mt]);
                    acc[mt] = MFMA(ao[mt][kk], bl[kk], acc[mt]);
                }
#pragma unroll
            for (int mt = 0; mt < 4; mt++)
#pragma unroll
                for (int rg = 0; rg < 4; rg++) {
                    const int row = mt*16 + rg0 + rg;
                    if (row < NTOK)
                        xattn[((size_t)wid * NTOK + row) * DIMC + col] =
                            f2bf(acc[mt][rg] + bias);
                }
        }
    }
}

// ---------------------------------------------------------------------------
// K2: LN2 + MLP + residual. 64 token rows/block; 4 blocks/CU (34.8 KB LDS,
// launch_bounds(256,4) caps VGPR at 128 for 4 waves/SIMD).
// ---------------------------------------------------------------------------
__global__ __launch_bounds__(256, 4)
void swin_mlp(const u16* __restrict__ xattn,
              const float* __restrict__ g2, const float* __restrict__ be2,
              const float* __restrict__ b1f, const float* __restrict__ b2f,
              const u16* __restrict__ wsw, float* __restrict__ out)
{
    __shared__ __align__(16) u16 s_X[64 * LDA];    // 25.6 KB (xln)
    __shared__ __align__(16) u16 s_H[64 * LDH2];   //  9.2 KB (h 64-col chunk)

    const int tid  = threadIdx.x;
    const int wv   = tid >> 6;
    const int lane = tid & 63;
    const int ar   = lane & 15;
    const int ak   = (lane >> 4) << 3;
    const int rg0  = (lane >> 4) << 2;
    const int base = blockIdx.x * 64;
    const u16* W1t = wsw + OFF_W1;
    const u16* W2t = wsw + OFF_W2;

    // ---- LN2 over 64 token rows ----
    for (int t = wv; t < 64; t += 4) {
        const u16* src = xattn + (size_t)(base + t) * DIMC;
        float v0 = bf2f(src[lane]);
        float v1 = bf2f(src[lane + 64]);
        float v2 = bf2f(src[lane + 128]);
        float s  = v0 + v1 + v2;
        float s2 = v0*v0 + v1*v1 + v2*v2;
#pragma unroll
        for (int off = 32; off > 0; off >>= 1) {
            s  += __shfl_xor(s,  off);
            s2 += __shfl_xor(s2, off);
        }
        const float mu   = s * (1.f / 192.f);
        const float rstd = rsqrtf(s2 * (1.f / 192.f) - mu * mu + 1e-5f);
        s_X[t*LDA + lane      ] = f2bf((v0-mu)*rstd*g2[lane]     + be2[lane]);
        s_X[t*LDA + lane + 64 ] = f2bf((v1-mu)*rstd*g2[lane+64]  + be2[lane+64]);
        s_X[t*LDA + lane + 128] = f2bf((v2-mu)*rstd*g2[lane+128] + be2[lane+128]);
    }
    __syncthreads();

    // ---- MLP: 12 hidden-chunks of 64; accO in regs across chunks ----
    f32x4 accO[3][4];
#pragma unroll
    for (int i = 0; i < 3; i++)
#pragma unroll
        for (int m = 0; m < 4; m++) accO[i][m] = 0;

    for (int cc = 0; cc < 12; cc++) {
        // MLP1: 1 col-tile per wave
        {
            const int ncol = wv*16 + ar;               // 0..63 within chunk
            const int ngl  = cc*64 + ncol;
            const float bias = b1f[ngl];
            const u16* wc = W1t + (size_t)ngl * 384;
            f32x4 hacc[4];
#pragma unroll
            for (int mt = 0; mt < 4; mt++) hacc[mt] = 0;
#pragma unroll
            for (int kh = 0; kh < 2; kh++)
#pragma unroll
                for (int kk = 0; kk < 3; kk++) {
                    const int ko = kh*96 + kk*32 + ak;
                    bf16x8 bh = *(const bf16x8*)&wc[ko];
                    bf16x8 bl = *(const bf16x8*)&wc[192 + ko];
#pragma unroll
                    for (int mt = 0; mt < 4; mt++) {
                        bf16x8 a = *(const bf16x8*)&s_X[(mt*16 + ar)*LDA + ko];
                        hacc[mt] = MFMA(a, bh, hacc[mt]);
                        hacc[mt] = MFMA(a, bl, hacc[mt]);
                    }
                }
#pragma unroll
            for (int mt = 0; mt < 4; mt++)
#pragma unroll
                for (int rg = 0; rg < 4; rg++) {
                    const float z = hacc[mt][rg] + bias;
                    const float ge = 0.5f * z * (1.f + erff(z * 0.70710678118654752f));
                    s_H[(mt*16 + rg0 + rg)*LDH2 + ncol] = f2bf(ge);
                }
        }
        __syncthreads();
        // MLP2 partial over this 64-wide K chunk
        {
#pragma unroll
            for (int ntl = 0; ntl < 3; ntl++) {
                const int col = (wv*3 + ntl)*16 + ar;
                const u16* wc2 = W2t + (size_t)col * 1536 + cc*64;
#pragma unroll
                for (int kk = 0; kk < 2; kk++) {
                    bf16x8 bh = *(const bf16x8*)&wc2[kk*32 + ak];
                    bf16x8 bl = *(const bf16x8*)&wc2[768 + kk*32 + ak];
#pragma unroll
                    for (int mt = 0; mt < 4; mt++) {
                        bf16x8 ah = *(const bf16x8*)&s_H[(mt*16 + ar)*LDH2 + kk*32 + ak];
                        accO[ntl][mt] = MFMA(ah, bh, accO[ntl][mt]);
                        accO[ntl][mt] = MFMA(ah, bl, accO[ntl][mt]);
                    }
                }
            }
        }
        __syncthreads();
    }

    // ---- epilogue: out = accO + b2 + residual, reverse-shift scatter ----
#pragma unroll
    for (int ntl = 0; ntl < 3; ntl++) {
        const int col = (wv*3 + ntl)*16 + ar;
        const float bias = b2f[col];
#pragma unroll
        for (int mt = 0; mt < 4; mt++)
#pragma unroll
            for (int rg = 0; rg < 4; rg++) {
                const int grow = base + mt*16 + rg0 + rg;
                const int w = grow / 49, t = grow - w * 49;
                const int bb = w >> 6, wi = (w >> 3) & 7, wj = w & 7;
                const int pi = t / 7, pj = t - pi * 7;
                const int di = (wi * WSZ + pi + SSH) % HH;
                const int dj = (wj * WSZ + pj + SSH) % HH;
                out[((size_t)bb * LTOT + di * HH + dj) * DIMC + col] =
                    accO[ntl][mt][rg] + bias + bf2f(xattn[(size_t)grow * DIMC + col]);
            }
    }
}

// ---------------------------------------------------------------------------
// Fallback: round-6 monolithic fused kernel (2 blocks/CU), if ws too small
// for the xattn buffer.
// ---------------------------------------------------------------------------
__global__ __launch_bounds__(256, 2)
void swin_mono(const float* __restrict__ x,
               const float* __restrict__ qkv_b, const float* __restrict__ proj_b,
               const float* __restrict__ g1, const float* __restrict__ be1,
               const float* __restrict__ g2, const float* __restrict__ be2,
               const float* __restrict__ b1f, const float* __restrict__ b2f,
               const u16* __restrict__ wsw, float* __restrict__ out)
{
    __shared__ __align__(16) u16 s_A[64 * LDA];
    __shared__ __align__(16) u16 s_Q[64 * LDA];
    __shared__ __align__(16) u16 s_R3[64 * LDA];

    float* const Sf  = (float*)s_R3;
    u16*  const PU   = s_R3;
    u16*  const Vt   = s_R3 + 64 * LDPU;
    u16*  const s_H  = s_R3;
    u16*  const s_XW = s_Q;

    const int wid = blockIdx.x;
    const int b  = wid >> 6;
    const int wi = (wid >> 3) & 7;
    const int wj = wid & 7;
    const int tid  = threadIdx.x;
    const int wv   = tid >> 6;
    const int lane = tid & 63;
    const int ar   = lane & 15;
    const int ak   = (lane >> 4) << 3;
    const int rg0  = (lane >> 4) << 2;

    const u16* Wpt = wsw + OFF_PW;
    const u16* W1t = wsw + OFF_W1;
    const u16* W2t = wsw + OFF_W2;

    ln1_gather(x, g1, be1, s_A, b, wi, wj, wv, lane);
    __syncthreads();

    attn_all(s_A, s_Q, Sf, PU, Vt, wsw + OFF_QKV, qkv_b, tid, wv, ar, ak, rg0);

    // proj -> s_XW
    {
        bf16x8 ao[4][6];
#pragma unroll
        for (int mt = 0; mt < 4; mt++)
#pragma unroll
            for (int kk = 0; kk < 6; kk++)
                ao[mt][kk] = *(const bf16x8*)&s_A[(mt*16 + ar)*LDA + kk*32 + ak];
#pragma unroll
        for (int ntl = 0; ntl < 3; ntl++) {
            const int col = (wv*3 + ntl)*16 + ar;
            const float bias = proj_b[col];
            const u16* wc = Wpt + (size_t)col * 384;
            bf16x8 bh[6], bl[6];
#pragma unroll
            for (int kk = 0; kk < 6; kk++) {
                bh[kk] = *(const bf16x8*)&wc[kk*32 + ak];
                bl[kk] = *(const bf16x8*)&wc[192 + kk*32 + ak];
            }
            f32x4 acc[4];
#pragma unroll
            for (int mt = 0; mt < 4; mt++) acc[mt] = 0;
#pragma unroll
            for (int kk = 0; kk < 6; kk++)
#pragma unroll
                for (int mt = 0; mt < 4; mt++) {
                    acc[mt] = MFMA(ao[mt][kk], bh[kk], acc[mt]);
                    acc[mt] = MFMA(ao[mt][kk], bl[kk], acc[mt]);
                }
#pragma unroll
            for (int mt = 0; mt < 4; mt++)
#pragma unroll
                for (int rg = 0; rg < 4; rg++)
                    s_XW[(mt*16 + rg0 + rg)*LDA + col] = f2bf(acc[mt][rg] + bias);
        }
    }
    __syncthreads();

    // LN2 -> s_A
    for (int t = wv; t < NTOK; t += 4) {
        float v0 = bf2f(s_XW[t*LDA + lane      ]);
        float v1 = bf2f(s_XW[t*LDA + lane + 64 ]);
        float v2 = bf2f(s_XW[t*LDA + lane + 128]);
        float s  = v0 + v1 + v2;
        float s2 = v0*v0 + v1*v1 + v2*v2;
#pragma unroll
        for (int off = 32; off > 0; off >>= 1) {
            s  += __shfl_xor(s,  off);
            s2 += __shfl_xor(s2, off);
        }
        const float mu   = s * (1.f / 192.f);
        const float rstd = rsqrtf(s2 * (1.f / 192.f) - mu * mu + 1e-5f);
        s_A[t*LDA + lane      ] = f2bf((v0-mu)*rstd*g2[lane]     + be2[lane]);
        s_A[t*LDA + lane + 64 ] = f2bf((v1-mu)*rstd*g2[lane+64]  + be2[lane+64]);
        s_A[t*LDA + lane + 128] = f2bf((v2-mu)*rstd*g2[lane+128] + be2[lane+128]);
    }
    __syncthreads();

    // MLP (4 chunks of 192)
    f32x4 accO[3][4];
#pragma unroll
    for (int i = 0; i < 3; i++)
#pragma unroll
        for (int m = 0; m < 4; m++) accO[i][m] = 0;

    for (int cc = 0; cc < 4; cc++) {
        {
            bf16x8 ax[4][6];
#pragma unroll
            for (int mt = 0; mt < 4; mt++)
#pragma unroll
                for (int kk = 0; kk < 6; kk++)
                    ax[mt][kk] = *(const bf16x8*)&s_A[(mt*16 + ar)*LDA + kk*32 + ak];
#pragma unroll
            for (int ntl = 0; ntl < 3; ntl++) {
                const int ncol = (wv*3 + ntl)*16 + ar;
                const int ngl  = cc*192 + ncol;
                const float bias = b1f[ngl];
                const u16* wc = W1t + (size_t)ngl * 384;
                bf16x8 bh[6], bl[6];
#pragma unroll
                for (int kk = 0; kk < 6; kk++) {
                    bh[kk] = *(const bf16x8*)&wc[kk*32 + ak];
                    bl[kk] = *(const bf16x8*)&wc[192 + kk*32 + ak];
                }
                f32x4 acc[4];
#pragma unroll
                for (int mt = 0; mt < 4; mt++) acc[mt] = 0;
#pragma unroll
                for (int kk = 0; kk < 6; kk++)
#pragma unroll
                    for (int mt = 0; mt < 4; mt++) {
                        acc[mt] = MFMA(ax[mt][kk], bh[kk], acc[mt]);
                        acc[mt] = MFMA(ax[mt][kk], bl[kk], acc[mt]);
                    }
#pragma unroll
                for (int mt = 0; mt < 4; mt++)
#pragma unroll
                    for (int rg = 0; rg < 4; rg++) {
                        const float z = acc[mt][rg] + bias;
                        const float ge = 0.5f * z * (1.f + erff(z * 0.70710678118654752f));
                        s_H[(mt*16 + rg0 + rg)*LDA + ncol] = f2bf(ge);
                    }
            }
        }
        __syncthreads();
        {
            bf16x8 ah[4][6];
#pragma unroll
            for (int mt = 0; mt < 4; mt++)
#pragma unroll
                for (int kk = 0; kk < 6; kk++)
                    ah[mt][kk] = *(const bf16x8*)&s_H[(mt*16 + ar)*LDA + kk*32 + ak];
#pragma unroll
            for (int ntl = 0; ntl < 3; ntl++) {
                const int col = (wv*3 + ntl)*16 + ar;
                const u16* wc = W2t + (size_t)col * 1536 + cc*192;
                bf16x8 bh[6], bl[6];
#pragma unroll
                for (int kk = 0; kk < 6; kk++) {
                    bh[kk] = *(const bf16x8*)&wc[kk*32 + ak];
                    bl[kk] = *(const bf16x8*)&wc[768 + kk*32 + ak];
                }
#pragma unroll
                for (int kk = 0; kk < 6; kk++)
#pragma unroll
                    for (int mt = 0; mt < 4; mt++) {
                        accO[ntl][mt] = MFMA(ah[mt][kk], bh[kk], accO[ntl][mt]);
                        accO[ntl][mt] = MFMA(ah[mt][kk], bl[kk], accO[ntl][mt]);
                    }
            }
        }
        __syncthreads();
    }

#pragma unroll
    for (int ntl = 0; ntl < 3; ntl++) {
        const int col = (wv*3 + ntl)*16 + ar;
        const float bias = b2f[col];
#pragma unroll
        for (int mt = 0; mt < 4; mt++)
#pragma unroll
            for (int rg = 0; rg < 4; rg++) {
                const int row = mt*16 + rg0 + rg;
                if (row < NTOK) {
                    const int pi = row / 7, pj = row - pi * 7;
                    const int di = (wi * WSZ + pi + SSH) % HH;
                    const int dj = (wj * WSZ + pj + SSH) % HH;
                    out[((size_t)b * LTOT + di * HH + dj) * DIMC + col] =
                        accO[ntl][mt][rg] + bias + bf2f(s_XW[row*LDA + col]);
                }
            }
    }
}

extern "C" void kernel_launch(void* const* d_in, const int* in_sizes, int n_in,
                              void* d_out, int out_size, void* d_ws, size_t ws_size,
                              hipStream_t stream)
{
    const float* x      = (const float*)d_in[0];
    const float* qkv_w  = (const float*)d_in[1];
    const float* qkv_b  = (const float*)d_in[2];
    const float* proj_w = (const float*)d_in[3];
    const float* proj_b = (const float*)d_in[4];
    const float* g1     = (const float*)d_in[5];
    const float* be1    = (const float*)d_in[6];
    const float* g2     = (const float*)d_in[7];
    const float* be2    = (const float*)d_in[8];
    const float* w1     = (const float*)d_in[9];
    const float* b1     = (const float*)d_in[10];
    const float* w2     = (const float*)d_in[11];
    const float* b2     = (const float*)d_in[12];
    float* out = (float*)d_out;

    cvt_weights<<<256, 256, 0, stream>>>(qkv_w, proj_w, w1, w2, (u16*)d_ws);

    if (ws_size >= (size_t)WS_BYTES + XATTN_BYTES) {
        u16* xattn = (u16*)d_ws + WS_ELEMS;
        swin_attn<<<NWIN_T, 256, 0, stream>>>(x, qkv_b, proj_b, g1, be1,
                                              (const u16*)d_ws, xattn);
        swin_mlp<<<NTOK * NWIN_T / 64, 256, 0, stream>>>(xattn, g2, be2, b1, b2,
                                                         (const u16*)d_ws, out);
    } else {
        swin_mono<<<NWIN_T, 256, 0, stream>>>(x, qkv_b, proj_b, g1, be1, g2, be2,
                                              b1, b2, (const u16*)d_ws, out);
    }
}

// Round 9
// 349.809 us; speedup vs baseline: 39.1176x; 1.3559x over previous
//
#include <hip/hip_runtime.h>

typedef unsigned short u16;
typedef unsigned int   u32;
typedef __attribute__((ext_vector_type(8))) short bf16x8;
typedef __attribute__((ext_vector_type(4))) float f32x4;

#define DIMC   192
#define HH     56
#define WSZ    7
#define SSH    3
#define NTOK   49
#define NWIN_T 2048
#define HIDDEN 768
#define LTOT   3136

#define LDA    200    // u16 row stride, [64][<=192] tiles (400B rows)
#define LDSS   68     // f32 row stride of S
#define LDPU   136    // u16 view (2*LDSS): hi cols 0-63, lo cols 64-127
#define LDVT   72     // u16 row stride of V^T

// ws layout (u16 elems): bf16 W^T[N][K] (hi only; split-P keeps accuracy)
#define OFF_QKV 0                         // 576 cols * 192
#define OFF_PW  110592                    // + 192 * 192
#define OFF_W1  147456                    // + 768 * 192
#define OFF_W2  294912                    // + 192 * 768
#define WS_ELEMS 442368
#define WS_BYTES (WS_ELEMS * 2)
#define XATTN_BYTES ((size_t)NWIN_T * NTOK * DIMC * 2)   // 38.5 MB bf16

#define MFMA(a,b,c) __builtin_amdgcn_mfma_f32_16x16x32_bf16((a),(b),(c),0,0,0)

__device__ __forceinline__ float bf2f(u16 u) {
    union { u32 i; float f; } v; v.i = ((u32)u) << 16; return v.f;
}
__device__ __forceinline__ u16 f2bf(float f) {
    union { float ff; u32 i; } v; v.ff = f;
    u32 x = v.i;
    return (u16)((x + 0x7FFFu + ((x >> 16) & 1u)) >> 16);  // RNE
}

// ---------------------------------------------------------------------------
// Prep: fp32 [K][N] weights -> bf16 W^T [N][K] in ws.
// ---------------------------------------------------------------------------
__global__ void cvt_weights(const float* __restrict__ qkv_w,
                            const float* __restrict__ proj_w,
                            const float* __restrict__ w1,
                            const float* __restrict__ w2,
                            u16* __restrict__ ws)
{
    const int idx = blockIdx.x * blockDim.x + threadIdx.x;
    const int stride = gridDim.x * blockDim.x;
    for (int i = idx; i < 110592; i += stride) {        // qkv [192][576]
        int k = i / 576, n = i - k * 576;
        ws[OFF_QKV + n * 192 + k] = f2bf(qkv_w[i]);
    }
    for (int i = idx; i < 36864; i += stride) {         // proj [192][192]
        int k = i / 192, n = i - k * 192;
        ws[OFF_PW + n * 192 + k] = f2bf(proj_w[i]);
    }
    for (int i = idx; i < 147456; i += stride) {        // w1 [192][768]
        int k = i / 768, n = i - k * 768;
        ws[OFF_W1 + n * 192 + k] = f2bf(w1[i]);
    }
    for (int i = idx; i < 147456; i += stride) {        // w2 [768][192]
        int k = i / 192, n = i - k * 192;
        ws[OFF_W2 + n * 768 + k] = f2bf(w2[i]);
    }
}

// ---------------------------------------------------------------------------
// P1: gather (shift -SSH) + LN1 -> s_A [64][192]; pad rows 49..63 zeroed.
// ---------------------------------------------------------------------------
__device__ __forceinline__ void ln1_gather(
    const float* __restrict__ x, const float* __restrict__ g1,
    const float* __restrict__ be1, u16* __restrict__ s_A,
    int b, int wi, int wj, int wv, int lane)
{
    for (int t = wv; t < 64; t += 4) {
        if (t < NTOK) {
            const int pi = t / 7, pj = t - pi * 7;
            const int si = (wi * WSZ + pi + SSH) % HH;
            const int sj = (wj * WSZ + pj + SSH) % HH;
            const float* src = x + ((size_t)b * LTOT + si * HH + sj) * DIMC;
            float v0 = src[lane], v1 = src[lane + 64], v2 = src[lane + 128];
            float s  = v0 + v1 + v2;
            float s2 = v0 * v0 + v1 * v1 + v2 * v2;
#pragma unroll
            for (int off = 32; off > 0; off >>= 1) {
                s  += __shfl_xor(s,  off);
                s2 += __shfl_xor(s2, off);
            }
            const float mu   = s * (1.f / 192.f);
            const float rstd = rsqrtf(s2 * (1.f / 192.f) - mu * mu + 1e-5f);
            s_A[t*LDA + lane      ] = f2bf((v0-mu)*rstd*g1[lane]     + be1[lane]);
            s_A[t*LDA + lane + 64 ] = f2bf((v1-mu)*rstd*g1[lane+64]  + be1[lane+64]);
            s_A[t*LDA + lane + 128] = f2bf((v2-mu)*rstd*g1[lane+128] + be1[lane+128]);
        } else {
            s_A[t*LDA + lane] = 0; s_A[t*LDA + lane + 64] = 0; s_A[t*LDA + lane + 128] = 0;
        }
    }
}

// ---------------------------------------------------------------------------
// attention: xn frags hoisted to regs; 3 QKV groups x 2 heads; MFMA QK^T,
// wave-parallel fp32 softmax, split hi/lo P MFMA PV. O ends in s_A.
// ---------------------------------------------------------------------------
__device__ __forceinline__ void attn_all(
    u16* __restrict__ s_A, u16* __restrict__ s_Q,
    float* __restrict__ Sf, u16* __restrict__ PU, u16* __restrict__ Vt,
    const u16* __restrict__ Wqkvt, const float* __restrict__ qkv_b,
    int tid, int wv, int ar, int ak, int rg0)
{
    const float scale = 0.1767766952966369f;   // 1/sqrt(32)
    f32x4 o[12];

    // hoisted xn fragments (s_A holds xn through all QKV groups)
    bf16x8 ax[4][6];
#pragma unroll
    for (int mt = 0; mt < 4; mt++)
#pragma unroll
        for (int kk = 0; kk < 6; kk++)
            ax[mt][kk] = *(const bf16x8*)&s_A[(mt*16 + ar)*LDA + kk*32 + ak];

#pragma unroll
    for (int G = 0; G < 3; G++) {
        // ---- QKV group G -> s_Q cols [0:64)=Q [64:128)=K [128:192)=V ----
#pragma unroll
        for (int tl = 0; tl < 3; tl++) {
            const int tt = wv*3 + tl;
            const int section = tt >> 2, idxq = tt & 3;
            const int gcol = section*192 + G*64 + idxq*16 + ar;
            const int lcol = section*64 + idxq*16 + ar;
            const float bias = qkv_b[gcol];
            const u16* wc = Wqkvt + (size_t)gcol * 192;
            f32x4 acc[4];
#pragma unroll
            for (int mt = 0; mt < 4; mt++) acc[mt] = 0;
#pragma unroll
            for (int kk = 0; kk < 6; kk++) {
                bf16x8 bh = *(const bf16x8*)&wc[kk*32 + ak];
#pragma unroll
                for (int mt = 0; mt < 4; mt++)
                    acc[mt] = MFMA(ax[mt][kk], bh, acc[mt]);
            }
#pragma unroll
            for (int mt = 0; mt < 4; mt++)
#pragma unroll
                for (int rg = 0; rg < 4; rg++)
                    s_Q[(mt*16 + rg0 + rg)*LDA + lcol] = f2bf(acc[mt][rg] + bias);
        }
        __syncthreads();

#pragma unroll
        for (int HL = 0; HL < 2; HL++) {
            // ---- S = scale * Q K^T ; wave wv owns col-tile wv ----
            {
                bf16x8 bk = *(const bf16x8*)&s_Q[(wv*16 + ar)*LDA + 64 + HL*32 + ak];
#pragma unroll
                for (int mt = 0; mt < 4; mt++) {
                    bf16x8 aq = *(const bf16x8*)&s_Q[(mt*16 + ar)*LDA + HL*32 + ak];
                    f32x4 sa; sa = 0;
                    sa = MFMA(aq, bk, sa);
#pragma unroll
                    for (int rg = 0; rg < 4; rg++)
                        Sf[(mt*16 + rg0 + rg)*LDSS + wv*16 + ar] = sa[rg] * scale;
                }
            }
            __syncthreads();
            // ---- softmax (4 lanes/row, regs) -> P hi|lo; Vt fill ----
            {
                const int row = tid >> 2, sub = tid & 3;
                if (row < NTOK) {
                    float e[16]; float m = -1e30f;
#pragma unroll
                    for (int i = 0; i < 16; i++) {
                        const int j = sub + 4*i;
                        e[i] = (j < NTOK) ? Sf[row*LDSS + j] : -1e30f;
                        m = fmaxf(m, e[i]);
                    }
                    m = fmaxf(m, __shfl_xor(m, 1));
                    m = fmaxf(m, __shfl_xor(m, 2));
                    float sum = 0.f;
#pragma unroll
                    for (int i = 0; i < 16; i++) { e[i] = __expf(e[i] - m); sum += e[i]; }
                    sum += __shfl_xor(sum, 1);
                    sum += __shfl_xor(sum, 2);
                    const float inv = 1.f / sum;
#pragma unroll
                    for (int i = 0; i < 16; i++) {
                        const int j = sub + 4*i;
                        const float p = e[i] * inv;   // 0 for j>=49 -> pad cols zero
                        const u16 hb = f2bf(p);
                        PU[row*LDPU + j] = hb;
                        PU[row*LDPU + 64 + j] = f2bf(p - bf2f(hb));
                    }
                }
                for (int i2 = tid; i2 < 2048; i2 += 256) {
                    const int d = i2 & 31, j = i2 >> 5;
                    Vt[d*LDVT + j] = (j < NTOK) ? s_Q[j*LDA + 128 + HL*32 + d] : (u16)0;
                }
            }
            __syncthreads();
            // ---- O = (Phi+Plo) @ V : 8 tiles over 4 waves, 2 per wave ----
            {
                const int dcol = (wv & 1)*16 + ar;
                const int mtb = (wv >> 1) << 1;
#pragma unroll
                for (int mi = 0; mi < 2; mi++) {
                    f32x4 accv; accv = 0;
#pragma unroll
                    for (int kk = 0; kk < 2; kk++) {
                        bf16x8 ph = *(const bf16x8*)&PU[((mtb+mi)*16 + ar)*LDPU + kk*32 + ak];
                        bf16x8 pl = *(const bf16x8*)&PU[((mtb+mi)*16 + ar)*LDPU + 64 + kk*32 + ak];
                        bf16x8 bv = *(const bf16x8*)&Vt[dcol*LDVT + kk*32 + ak];
                        accv = MFMA(ph, bv, accv);
                        accv = MFMA(pl, bv, accv);
                    }
                    o[(G*2 + HL)*2 + mi] = accv;
                }
            }
            __syncthreads();
        }
    }

    // ---- O -> s_A (xn dead; pad rows receive zeros since P pad rows = 0) ----
    {
        const int mtb = (wv >> 1) << 1;
        const int cbase = (wv & 1)*16 + ar;
#pragma unroll
        for (int hp = 0; hp < 6; hp++) {
            const int col = hp*32 + cbase;
#pragma unroll
            for (int mi = 0; mi < 2; mi++)
#pragma unroll
                for (int rg = 0; rg < 4; rg++)
                    s_A[((mtb+mi)*16 + rg0 + rg)*LDA + col] = f2bf(o[hp*2 + mi][rg]);
        }
    }
    __syncthreads();
}

// ---------------------------------------------------------------------------
// K1: LN1 + QKV + attention + proj -> xattn (bf16, window-major [2048][49][192])
// ---------------------------------------------------------------------------
__global__ __launch_bounds__(256, 2)
void swin_attn(const float* __restrict__ x,
               const float* __restrict__ qkv_b, const float* __restrict__ proj_b,
               const float* __restrict__ g1, const float* __restrict__ be1,
               const u16* __restrict__ wsw, u16* __restrict__ xattn)
{
    __shared__ __align__(16) u16 s_A[64 * LDA];                 // 25.6 KB
    __shared__ __align__(16) u16 s_Q[64 * LDA];                 // 25.6 KB
    __shared__ __align__(16) u16 s_R3[64 * LDPU + 32 * LDVT];   // 22.0 KB

    float* const Sf = (float*)s_R3;
    u16*  const PU  = s_R3;
    u16*  const Vt  = s_R3 + 64 * LDPU;

    const int wid = blockIdx.x;
    const int b  = wid >> 6;
    const int wi = (wid >> 3) & 7;
    const int wj = wid & 7;
    const int tid  = threadIdx.x;
    const int wv   = tid >> 6;
    const int lane = tid & 63;
    const int ar   = lane & 15;
    const int ak   = (lane >> 4) << 3;
    const int rg0  = (lane >> 4) << 2;

    ln1_gather(x, g1, be1, s_A, b, wi, wj, wv, lane);
    __syncthreads();

    attn_all(s_A, s_Q, Sf, PU, Vt, wsw + OFF_QKV, qkv_b, tid, wv, ar, ak, rg0);

    // ---- proj: XW = O @ Wp + b -> global xattn (bf16) ----
    {
        const u16* Wpt = wsw + OFF_PW;
        bf16x8 ao[4][6];
#pragma unroll
        for (int mt = 0; mt < 4; mt++)
#pragma unroll
            for (int kk = 0; kk < 6; kk++)
                ao[mt][kk] = *(const bf16x8*)&s_A[(mt*16 + ar)*LDA + kk*32 + ak];
#pragma unroll
        for (int ntl = 0; ntl < 3; ntl++) {
            const int col = (wv*3 + ntl)*16 + ar;
            const float bias = proj_b[col];
            const u16* wc = Wpt + (size_t)col * 192;
            f32x4 acc[4];
#pragma unroll
            for (int mt = 0; mt < 4; mt++) acc[mt] = 0;
#pragma unroll
            for (int kk = 0; kk < 6; kk++) {
                bf16x8 bh = *(const bf16x8*)&wc[kk*32 + ak];
#pragma unroll
                for (int mt = 0; mt < 4; mt++)
                    acc[mt] = MFMA(ao[mt][kk], bh, acc[mt]);
            }
#pragma unroll
            for (int mt = 0; mt < 4; mt++)
#pragma unroll
                for (int rg = 0; rg < 4; rg++) {
                    const int row = mt*16 + rg0 + rg;
                    if (row < NTOK)
                        xattn[((size_t)wid * NTOK + row) * DIMC + col] =
                            f2bf(acc[mt][rg] + bias);
                }
        }
    }
}

// ---------------------------------------------------------------------------
// K2: LN2 + MLP + residual. 64 token rows/block, hidden chunk = 192
// (4 chunks, 8 barriers); per-kk A-frag reuse (1 ds_read : 3 MFMA).
// ---------------------------------------------------------------------------
__global__ __launch_bounds__(256, 3)
void swin_mlp(const u16* __restrict__ xattn,
              const float* __restrict__ g2, const float* __restrict__ be2,
              const float* __restrict__ b1f, const float* __restrict__ b2f,
              const u16* __restrict__ wsw, float* __restrict__ out)
{
    __shared__ __align__(16) u16 s_X[64 * LDA];    // 25.6 KB (xln)
    __shared__ __align__(16) u16 s_H[64 * LDA];    // 25.6 KB (h 192-col chunk)

    const int tid  = threadIdx.x;
    const int wv   = tid >> 6;
    const int lane = tid & 63;
    const int ar   = lane & 15;
    const int ak   = (lane >> 4) << 3;
    const int rg0  = (lane >> 4) << 2;
    const int base = blockIdx.x * 64;
    const u16* W1t = wsw + OFF_W1;
    const u16* W2t = wsw + OFF_W2;

    // ---- LN2 over 64 token rows ----
    for (int t = wv; t < 64; t += 4) {
        const u16* src = xattn + (size_t)(base + t) * DIMC;
        float v0 = bf2f(src[lane]);
        float v1 = bf2f(src[lane + 64]);
        float v2 = bf2f(src[lane + 128]);
        float s  = v0 + v1 + v2;
        float s2 = v0*v0 + v1*v1 + v2*v2;
#pragma unroll
        for (int off = 32; off > 0; off >>= 1) {
            s  += __shfl_xor(s,  off);
            s2 += __shfl_xor(s2, off);
        }
        const float mu   = s * (1.f / 192.f);
        const float rstd = rsqrtf(s2 * (1.f / 192.f) - mu * mu + 1e-5f);
        s_X[t*LDA + lane      ] = f2bf((v0-mu)*rstd*g2[lane]     + be2[lane]);
        s_X[t*LDA + lane + 64 ] = f2bf((v1-mu)*rstd*g2[lane+64]  + be2[lane+64]);
        s_X[t*LDA + lane + 128] = f2bf((v2-mu)*rstd*g2[lane+128] + be2[lane+128]);
    }
    __syncthreads();

    // ---- MLP: 4 hidden-chunks of 192; accO in regs across chunks ----
    f32x4 accO[3][4];
#pragma unroll
    for (int i = 0; i < 3; i++)
#pragma unroll
        for (int m = 0; m < 4; m++) accO[i][m] = 0;

    for (int cc = 0; cc < 4; cc++) {
        // MLP1 chunk: 3 col-tiles per wave, A-frag reused across tiles per kk
        {
            f32x4 acc1[3][4];
#pragma unroll
            for (int i = 0; i < 3; i++)
#pragma unroll
                for (int m = 0; m < 4; m++) acc1[i][m] = 0;
#pragma unroll
            for (int kk = 0; kk < 6; kk++) {
                bf16x8 a4[4];
#pragma unroll
                for (int mt = 0; mt < 4; mt++)
                    a4[mt] = *(const bf16x8*)&s_X[(mt*16 + ar)*LDA + kk*32 + ak];
#pragma unroll
                for (int ntl = 0; ntl < 3; ntl++) {
                    const int ngl = cc*192 + (wv*3 + ntl)*16 + ar;
                    bf16x8 w = *(const bf16x8*)&W1t[(size_t)ngl * 192 + kk*32 + ak];
#pragma unroll
                    for (int mt = 0; mt < 4; mt++)
                        acc1[ntl][mt] = MFMA(a4[mt], w, acc1[ntl][mt]);
                }
            }
#pragma unroll
            for (int ntl = 0; ntl < 3; ntl++) {
                const int ncol = (wv*3 + ntl)*16 + ar;
                const float bias = b1f[cc*192 + ncol];
#pragma unroll
                for (int mt = 0; mt < 4; mt++)
#pragma unroll
                    for (int rg = 0; rg < 4; rg++) {
                        const float z = acc1[ntl][mt][rg] + bias;
                        const float ge = 0.5f * z * (1.f + erff(z * 0.70710678118654752f));
                        s_H[(mt*16 + rg0 + rg)*LDA + ncol] = f2bf(ge);
                    }
            }
        }
        __syncthreads();
        // MLP2 partial over this 192-wide K chunk
        {
#pragma unroll
            for (int kk = 0; kk < 6; kk++) {
                bf16x8 a4[4];
#pragma unroll
                for (int mt = 0; mt < 4; mt++)
                    a4[mt] = *(const bf16x8*)&s_H[(mt*16 + ar)*LDA + kk*32 + ak];
#pragma unroll
                for (int ntl = 0; ntl < 3; ntl++) {
                    const int col = (wv*3 + ntl)*16 + ar;
                    bf16x8 w = *(const bf16x8*)&W2t[(size_t)col * 768 + cc*192 + kk*32 + ak];
#pragma unroll
                    for (int mt = 0; mt < 4; mt++)
                        accO[ntl][mt] = MFMA(a4[mt], w, accO[ntl][mt]);
                }
            }
        }
        __syncthreads();
    }

    // ---- epilogue: out = accO + b2 + residual, reverse-shift scatter ----
#pragma unroll
    for (int ntl = 0; ntl < 3; ntl++) {
        const int col = (wv*3 + ntl)*16 + ar;
        const float bias = b2f[col];
#pragma unroll
        for (int mt = 0; mt < 4; mt++)
#pragma unroll
            for (int rg = 0; rg < 4; rg++) {
                const int grow = base + mt*16 + rg0 + rg;
                const int w = grow / 49, t = grow - w * 49;
                const int bb = w >> 6, wi = (w >> 3) & 7, wj = w & 7;
                const int pi = t / 7, pj = t - pi * 7;
                const int di = (wi * WSZ + pi + SSH) % HH;
                const int dj = (wj * WSZ + pj + SSH) % HH;
                out[((size_t)bb * LTOT + di * HH + dj) * DIMC + col] =
                    accO[ntl][mt][rg] + bias + bf2f(xattn[(size_t)grow * DIMC + col]);
            }
    }
}

// ---------------------------------------------------------------------------
// Fallback: monolithic fused kernel (2 blocks/CU), if ws too small for xattn.
// ---------------------------------------------------------------------------
__global__ __launch_bounds__(256, 2)
void swin_mono(const float* __restrict__ x,
               const float* __restrict__ qkv_b, const float* __restrict__ proj_b,
               const float* __restrict__ g1, const float* __restrict__ be1,
               const float* __restrict__ g2, const float* __restrict__ be2,
               const float* __restrict__ b1f, const float* __restrict__ b2f,
               const u16* __restrict__ wsw, float* __restrict__ out)
{
    __shared__ __align__(16) u16 s_A[64 * LDA];
    __shared__ __align__(16) u16 s_Q[64 * LDA];
    __shared__ __align__(16) u16 s_R3[64 * LDA];

    float* const Sf  = (float*)s_R3;
    u16*  const PU   = s_R3;
    u16*  const Vt   = s_R3 + 64 * LDPU;
    u16*  const s_H  = s_R3;
    u16*  const s_XW = s_Q;

    const int wid = blockIdx.x;
    const int b  = wid >> 6;
    const int wi = (wid >> 3) & 7;
    const int wj = wid & 7;
    const int tid  = threadIdx.x;
    const int wv   = tid >> 6;
    const int lane = tid & 63;
    const int ar   = lane & 15;
    const int ak   = (lane >> 4) << 3;
    const int rg0  = (lane >> 4) << 2;

    const u16* Wpt = wsw + OFF_PW;
    const u16* W1t = wsw + OFF_W1;
    const u16* W2t = wsw + OFF_W2;

    ln1_gather(x, g1, be1, s_A, b, wi, wj, wv, lane);
    __syncthreads();

    attn_all(s_A, s_Q, Sf, PU, Vt, wsw + OFF_QKV, qkv_b, tid, wv, ar, ak, rg0);

    // proj -> s_XW
    {
        bf16x8 ao[4][6];
#pragma unroll
        for (int mt = 0; mt < 4; mt++)
#pragma unroll
            for (int kk = 0; kk < 6; kk++)
                ao[mt][kk] = *(const bf16x8*)&s_A[(mt*16 + ar)*LDA + kk*32 + ak];
#pragma unroll
        for (int ntl = 0; ntl < 3; ntl++) {
            const int col = (wv*3 + ntl)*16 + ar;
            const float bias = proj_b[col];
            const u16* wc = Wpt + (size_t)col * 192;
            f32x4 acc[4];
#pragma unroll
            for (int mt = 0; mt < 4; mt++) acc[mt] = 0;
#pragma unroll
            for (int kk = 0; kk < 6; kk++) {
                bf16x8 bh = *(const bf16x8*)&wc[kk*32 + ak];
#pragma unroll
                for (int mt = 0; mt < 4; mt++)
                    acc[mt] = MFMA(ao[mt][kk], bh, acc[mt]);
            }
#pragma unroll
            for (int mt = 0; mt < 4; mt++)
#pragma unroll
                for (int rg = 0; rg < 4; rg++)
                    s_XW[(mt*16 + rg0 + rg)*LDA + col] = f2bf(acc[mt][rg] + bias);
        }
    }
    __syncthreads();

    // LN2 -> s_A
    for (int t = wv; t < NTOK; t += 4) {
        float v0 = bf2f(s_XW[t*LDA + lane      ]);
        float v1 = bf2f(s_XW[t*LDA + lane + 64 ]);
        float v2 = bf2f(s_XW[t*LDA + lane + 128]);
        float s  = v0 + v1 + v2;
        float s2 = v0*v0 + v1*v1 + v2*v2;
#pragma unroll
        for (int off = 32; off > 0; off >>= 1) {
            s  += __shfl_xor(s,  off);
            s2 += __shfl_xor(s2, off);
        }
        const float mu   = s * (1.f / 192.f);
        const float rstd = rsqrtf(s2 * (1.f / 192.f) - mu * mu + 1e-5f);
        s_A[t*LDA + lane      ] = f2bf((v0-mu)*rstd*g2[lane]     + be2[lane]);
        s_A[t*LDA + lane + 64 ] = f2bf((v1-mu)*rstd*g2[lane+64]  + be2[lane+64]);
        s_A[t*LDA + lane + 128] = f2bf((v2-mu)*rstd*g2[lane+128] + be2[lane+128]);
    }
    __syncthreads();

    // MLP (4 chunks of 192)
    f32x4 accO[3][4];
#pragma unroll
    for (int i = 0; i < 3; i++)
#pragma unroll
        for (int m = 0; m < 4; m++) accO[i][m] = 0;

    for (int cc = 0; cc < 4; cc++) {
        {
            f32x4 acc1[3][4];
#pragma unroll
            for (int i = 0; i < 3; i++)
#pragma unroll
                for (int m = 0; m < 4; m++) acc1[i][m] = 0;
#pragma unroll
            for (int kk = 0; kk < 6; kk++) {
                bf16x8 a4[4];
#pragma unroll
                for (int mt = 0; mt < 4; mt++)
                    a4[mt] = *(const bf16x8*)&s_A[(mt*16 + ar)*LDA + kk*32 + ak];
#pragma unroll
                for (int ntl = 0; ntl < 3; ntl++) {
                    const int ngl = cc*192 + (wv*3 + ntl)*16 + ar;
                    bf16x8 w = *(const bf16x8*)&W1t[(size_t)ngl * 192 + kk*32 + ak];
#pragma unroll
                    for (int mt = 0; mt < 4; mt++)
                        acc1[ntl][mt] = MFMA(a4[mt], w, acc1[ntl][mt]);
                }
            }
#pragma unroll
            for (int ntl = 0; ntl < 3; ntl++) {
                const int ncol = (wv*3 + ntl)*16 + ar;
                const float bias = b1f[cc*192 + ncol];
#pragma unroll
                for (int mt = 0; mt < 4; mt++)
#pragma unroll
                    for (int rg = 0; rg < 4; rg++) {
                        const float z = acc1[ntl][mt][rg] + bias;
                        const float ge = 0.5f * z * (1.f + erff(z * 0.70710678118654752f));
                        s_H[(mt*16 + rg0 + rg)*LDA + ncol] = f2bf(ge);
                    }
            }
        }
        __syncthreads();
        {
#pragma unroll
            for (int kk = 0; kk < 6; kk++) {
                bf16x8 a4[4];
#pragma unroll
                for (int mt = 0; mt < 4; mt++)
                    a4[mt] = *(const bf16x8*)&s_H[(mt*16 + ar)*LDA + kk*32 + ak];
#pragma unroll
                for (int ntl = 0; ntl < 3; ntl++) {
                    const int col = (wv*3 + ntl)*16 + ar;
                    bf16x8 w = *(const bf16x8*)&W2t[(size_t)col * 768 + cc*192 + kk*32 + ak];
#pragma unroll
                    for (int mt = 0; mt < 4; mt++)
                        accO[ntl][mt] = MFMA(a4[mt], w, accO[ntl][mt]);
                }
            }
        }
        __syncthreads();
    }

#pragma unroll
    for (int ntl = 0; ntl < 3; ntl++) {
        const int col = (wv*3 + ntl)*16 + ar;
        const float bias = b2f[col];
#pragma unroll
        for (int mt = 0; mt < 4; mt++)
#pragma unroll
            for (int rg = 0; rg < 4; rg++) {
                const int row = mt*16 + rg0 + rg;
                if (row < NTOK) {
                    const int pi = row / 7, pj = row - pi * 7;
                    const int di = (wi * WSZ + pi + SSH) % HH;
                    const int dj = (wj * WSZ + pj + SSH) % HH;
                    out[((size_t)b * LTOT + di * HH + dj) * DIMC + col] =
                        accO[ntl][mt][rg] + bias + bf2f(s_XW[row*LDA + col]);
                }
            }
    }
}

extern "C" void kernel_launch(void* const* d_in, const int* in_sizes, int n_in,
                              void* d_out, int out_size, void* d_ws, size_t ws_size,
                              hipStream_t stream)
{
    const float* x      = (const float*)d_in[0];
    const float* qkv_w  = (const float*)d_in[1];
    const float* qkv_b  = (const float*)d_in[2];
    const float* proj_w = (const float*)d_in[3];
    const float* proj_b = (const float*)d_in[4];
    const float* g1     = (const float*)d_in[5];
    const float* be1    = (const float*)d_in[6];
    const float* g2     = (const float*)d_in[7];
    const float* be2    = (const float*)d_in[8];
    const float* w1     = (const float*)d_in[9];
    const float* b1     = (const float*)d_in[10];
    const float* w2     = (const float*)d_in[11];
    const float* b2     = (const float*)d_in[12];
    float* out = (float*)d_out;

    cvt_weights<<<256, 256, 0, stream>>>(qkv_w, proj_w, w1, w2, (u16*)d_ws);

    if (ws_size >= (size_t)WS_BYTES + XATTN_BYTES) {
        u16* xattn = (u16*)d_ws + WS_ELEMS;
        swin_attn<<<NWIN_T, 256, 0, stream>>>(x, qkv_b, proj_b, g1, be1,
                                              (const u16*)d_ws, xattn);
        swin_mlp<<<NTOK * NWIN_T / 64, 256, 0, stream>>>(xattn, g2, be2, b1, b2,
                                                         (const u16*)d_ws, out);
    } else {
        swin_mono<<<NWIN_T, 256, 0, stream>>>(x, qkv_b, proj_b, g1, be1, g2, be2,
                                              b1, b2, (const u16*)d_ws, out);
    }
}